// Round 14
// baseline (2243.449 us; speedup 1.0000x reference)
//
#include <hip/hip_runtime.h>
#include <hip/hip_fp16.h>
#include <math.h>

#define NN 50000
#define EE 800000
#define GG 512

typedef _Float16 f16x8 __attribute__((ext_vector_type(8)));
typedef _Float16 f16x2 __attribute__((ext_vector_type(2)));
typedef float f32x4 __attribute__((ext_vector_type(4)));

#if defined(__has_builtin)
#if __has_builtin(__builtin_amdgcn_fdot2)
#define HAS_FDOT2 1
#endif
#endif

// fold 1/sqrt(64) * log2(e) into q so scores are in log2 domain
#define QSCALE 0.1803368801111244f

__device__ __forceinline__ float wave16_sum(float p) {
    p += __shfl_xor(p, 1);
    p += __shfl_xor(p, 2);
    p += __shfl_xor(p, 4);
    p += __shfl_xor(p, 8);
    return p;
}
__device__ __forceinline__ float2 h2f(unsigned int u) {
    __half2 h = *reinterpret_cast<__half2*>(&u);
    return __half22float2(h);
}
__device__ __forceinline__ unsigned short f2us(float x) {
    return __half_as_ushort(__float2half(x));
}
__device__ __forceinline__ float us2f(unsigned short u) {
    return __half2float(__ushort_as_half(u));
}
__device__ __forceinline__ f16x2 u2h2(unsigned int u) {
    union { unsigned int u; f16x2 h; } x; x.u = u; return x.h;
}
__device__ __forceinline__ float dot2acc(f16x2 a, f16x2 b, float c) {
#ifdef HAS_FDOT2
    return __builtin_amdgcn_fdot2(a, b, c, false);
#else
    return c + (float)a[0] * (float)b[0] + (float)a[1] * (float)b[1];
#endif
}
__device__ __forceinline__ float exp2fast(float x) {
    return __builtin_amdgcn_exp2f(x);
}

// ---------------- scans (CSR build) ----------------
__global__ void scan1(const int* __restrict__ deg, int* __restrict__ incl, int* __restrict__ bsum) {
    __shared__ int sh[256];
    int t = threadIdx.x;
    int n = blockIdx.x * 256 + t;
    int vv = (n < NN) ? deg[n] : 0;
    sh[t] = vv; __syncthreads();
    for (int off = 1; off < 256; off <<= 1) {
        int u = (t >= off) ? sh[t - off] : 0;
        __syncthreads();
        sh[t] += u;
        __syncthreads();
    }
    if (n < NN) incl[n] = sh[t];
    if (t == 255) bsum[blockIdx.x] = sh[255];
}

__global__ void scan2(int* __restrict__ bsum, int nblk) {
    __shared__ int sh[256];
    int t = threadIdx.x;
    int vv = (t < nblk) ? bsum[t] : 0;
    sh[t] = vv; __syncthreads();
    for (int off = 1; off < 256; off <<= 1) {
        int u = (t >= off) ? sh[t - off] : 0;
        __syncthreads();
        sh[t] += u;
        __syncthreads();
    }
    bsum[t] = sh[t];
}

__global__ void scan3(int* __restrict__ rowst, const int* __restrict__ deg,
                      const int* __restrict__ bsum, int* __restrict__ cursor) {
    int n = blockIdx.x * 256 + threadIdx.x;
    if (n >= NN) return;
    int off = (blockIdx.x > 0) ? bsum[blockIdx.x - 1] : 0;
    int excl = rowst[n] - deg[n] + off;
    rowst[n] = excl;
    cursor[n] = excl;
}

// ---------------- fused prep: x-cast || W-pack || degree count ----------------
// wt layout per layer: [448][64] fp16, wt[c][k] = W[k][c]; c: 0..127 q, 128..255 k, 256..383 v, 384..447 skip
#define WT_LSTRIDE (448 * 64)
#define XCAST_BLKS 3125   // NN*16/256
#define DEG_BLKS 3125     // EE/256
__global__ void prep_kernel(const float* __restrict__ x, unsigned short* __restrict__ xh,
                            const float* __restrict__ Wq, const float* __restrict__ Wk,
                            const float* __restrict__ Wv, const float* __restrict__ Ws,
                            unsigned short* __restrict__ wt,
                            const int* __restrict__ ei, int* __restrict__ deg) {
    __shared__ float lds_t[64][65];
    int b = blockIdx.x;
    if (b < XCAST_BLKS) {
        int i = b * 256 + threadIdx.x;
        float4 v = *(const float4*)(x + (size_t)i * 4);
        ushort4 o = make_ushort4(f2us(v.x), f2us(v.y), f2us(v.z), f2us(v.w));
        *(ushort4*)(xh + (size_t)i * 4) = o;
        return;
    }
    if (b < XCAST_BLKS + 21) {
        int tile = b - XCAST_BLKS;  // 0..20
        int l = tile / 7, ct = tile % 7;
        int c0 = ct * 64;
        int t = threadIdx.x;
        #pragma unroll
        for (int r = 0; r < 16; ++r) {
            int idx = r * 256 + t;
            int kk = idx >> 6, cc = idx & 63;
            int c = c0 + cc;
            float val;
            if (c < 384) {
                int m = c >> 7, col = c & 127;
                const float* W = (m == 0) ? Wq : ((m == 1) ? Wk : Wv);
                val = W[(size_t)l * 8192 + kk * 128 + col];
            } else {
                val = Ws[(size_t)l * 4096 + kk * 64 + (c - 384)];
            }
            lds_t[cc][kk] = val;
        }
        __syncthreads();
        #pragma unroll
        for (int r = 0; r < 16; ++r) {
            int idx = r * 256 + t;
            int cc = idx >> 6, kk = idx & 63;
            wt[((size_t)l * 448 + c0 + cc) * 64 + kk] = f2us(lds_t[cc][kk]);
        }
        return;
    }
    int e = (b - XCAST_BLKS - 21) * 256 + threadIdx.x;
    if (e < EE) atomicAdd(&deg[ei[EE + e]], 1);
}

// ---------------- MFMA GEMM (LDS-staged coalesced epilogue) || CSR fill ----------------
// kvh row layout (interleaved for agg): group j (0..15) holds halves [j*16, j*16+16):
//   k0[j*4..+3], k1[...], v0[...], v1[...]
#define GEMM_GRID_C 1563  // ceil(NN/32)
__global__ __launch_bounds__(256) void gemm_fill(
    const unsigned short* __restrict__ xh,
    const unsigned short* __restrict__ wt,
    const float* __restrict__ bq, const float* __restrict__ bk,
    const float* __restrict__ bv, const float* __restrict__ bsk,
    unsigned short* __restrict__ qh, unsigned short* __restrict__ kvh,
    unsigned short* __restrict__ skiph,
    const int* __restrict__ ei, int* __restrict__ cursor,
    unsigned short* __restrict__ esrc) {
    __shared__ __align__(16) unsigned short lds_q[32 * 128];
    __shared__ __align__(16) unsigned short lds_kv[32 * 256];
    __shared__ __align__(16) unsigned short lds_sk[32 * 64];
    if (blockIdx.x >= GEMM_GRID_C) {
        // CSR fill branch (only present in layer-0 launch)
        int e = (blockIdx.x - GEMM_GRID_C) * 256 + threadIdx.x;
        if (e < EE) {
            int s = ei[e], d = ei[EE + e];
            int pos = atomicAdd(&cursor[d], 1);
            esrc[pos] = (unsigned short)s;
        }
        return;
    }
    int t = threadIdx.x;
    int wave = t >> 6, lane = t & 63;
    int li = lane & 15, lh = lane >> 4;
    int brow = blockIdx.x * 32;
    int row0 = brow + (wave & 1) * 16;
    int ctbase = (wave >> 1) * 14;

    int arow = min(row0 + li, NN - 1);
    const unsigned short* ap = xh + (size_t)arow * 64 + lh * 8;
    f16x8 a0 = *(const f16x8*)(ap);
    f16x8 a1 = *(const f16x8*)(ap + 32);

    int rl0 = (wave & 1) * 16 + lh * 4;

    #pragma unroll 2
    for (int tt = 0; tt < 14; ++tt) {
        int c = (ctbase + tt) * 16 + li;
        const unsigned short* bp = wt + (size_t)c * 64 + lh * 8;
        f16x8 b0 = *(const f16x8*)(bp);
        f16x8 b1 = *(const f16x8*)(bp + 32);
        f32x4 d = {0.f, 0.f, 0.f, 0.f};
        d = __builtin_amdgcn_mfma_f32_16x16x32_f16(a0, b0, d, 0, 0, 0);
        d = __builtin_amdgcn_mfma_f32_16x16x32_f16(a1, b1, d, 0, 0, 0);
        if (c < 128) {
            float bias = bq[c];
            #pragma unroll
            for (int e = 0; e < 4; ++e)
                lds_q[(rl0 + e) * 128 + c] = f2us((d[e] + bias) * QSCALE);
        } else if (c < 256) {
            int ch = c - 128;
            float bias = bk[ch];
            int off = (ch < 64) ? ((ch >> 2) * 16 + (ch & 3))
                                : (((ch - 64) >> 2) * 16 + 4 + (ch & 3));
            #pragma unroll
            for (int e = 0; e < 4; ++e)
                lds_kv[(rl0 + e) * 256 + off] = f2us(d[e] + bias);
        } else if (c < 384) {
            int ch = c - 256;
            float bias = bv[ch];
            int off = 8 + ((ch < 64) ? ((ch >> 2) * 16 + (ch & 3))
                                     : (((ch - 64) >> 2) * 16 + 4 + (ch & 3)));
            #pragma unroll
            for (int e = 0; e < 4; ++e)
                lds_kv[(rl0 + e) * 256 + off] = f2us(d[e] + bias);
        } else {
            int ch = c - 384;
            float bias = bsk[ch];
            #pragma unroll
            for (int e = 0; e < 4; ++e)
                lds_sk[(rl0 + e) * 64 + ch] = f2us(d[e] + bias);
        }
    }
    __syncthreads();
    // coalesced write-out: rows brow..brow+31 contiguous in each output array
    #pragma unroll
    for (int i = t; i < 512; i += 256) {          // q: 32 rows x 128h = 512 x 16B
        int r = i >> 4, gr = brow + r;
        if (gr < NN)
            *(uint4*)(qh + (size_t)gr * 128 + (i & 15) * 8) = ((const uint4*)lds_q)[i];
    }
    #pragma unroll
    for (int i = t; i < 1024; i += 256) {         // kv: 32 rows x 256h = 1024 x 16B
        int r = i >> 5, gr = brow + r;
        if (gr < NN)
            *(uint4*)(kvh + (size_t)gr * 256 + (i & 31) * 8) = ((const uint4*)lds_kv)[i];
    }
    {
        int i = t;                                 // skip: 32 rows x 64h = 256 x 16B
        int r = i >> 3, gr = brow + r;
        if (i < 256 && gr < NN)
            *(uint4*)(skiph + (size_t)gr * 64 + (i & 7) * 8) = ((const uint4*)lds_sk)[i];
    }
}

// ---------------- per-node attention aggregation: persistent wave work-stealing ----------------
__global__ __launch_bounds__(256) void agg_kernel(
    const unsigned short* __restrict__ qh, const unsigned short* __restrict__ kvh,
    const unsigned short* __restrict__ skiph,
    const int* __restrict__ rowst, const int* __restrict__ deg,
    const unsigned short* __restrict__ esrc, const float* __restrict__ gamma,
    const float* __restrict__ beta, unsigned short* __restrict__ hout, int do_ln,
    int* __restrict__ ctr) {
    int lane = threadIdx.x & 63;
    int j = lane & 15;
    int slot = lane >> 4;

    for (;;) {
        int node = 0;
        if (lane == 0) node = atomicAdd(ctr, 1);
        node = __shfl(node, 0);
        if (node >= NN) return;

        // q (pre-scaled by 0.125*log2e): head0 dims j*4..+3, head1 at +64
        uint2 qu0 = *(const uint2*)(qh + (size_t)node * 128 + j * 4);
        uint2 qu1 = *(const uint2*)(qh + (size_t)node * 128 + 64 + j * 4);
        f16x2 q0a = u2h2(qu0.x), q0b = u2h2(qu0.y);
        f16x2 q1a = u2h2(qu1.x), q1b = u2h2(qu1.y);

        float m0 = -1e30f, m1 = -1e30f;
        float l0 = 0.f, l1 = 0.f;
        float acc0[4] = {0.f, 0.f, 0.f, 0.f};
        float acc1[4] = {0.f, 0.f, 0.f, 0.f};

        int st = rowst[node];
        int dg = deg[node];
        int last = dg - 1;
        for (int base = slot * 2; base < dg; base += 8) {
            int s0 = (int)esrc[st + min(base + 0, last)];
            int s1 = (int)esrc[st + min(base + 1, last)];
            const unsigned short* b0 = kvh + (size_t)s0 * 256 + j * 16;
            const unsigned short* b1 = kvh + (size_t)s1 * 256 + j * 16;
            uint4 A0 = *(const uint4*)(b0);       // k0[4],k1[4]
            uint4 B0 = *(const uint4*)(b0 + 8);   // v0[4],v1[4]
            uint4 A1 = *(const uint4*)(b1);
            uint4 B1 = *(const uint4*)(b1 + 8);

            float p00 = dot2acc(q0b, u2h2(A0.y), dot2acc(q0a, u2h2(A0.x), 0.f));
            float p01 = dot2acc(q1b, u2h2(A0.w), dot2acc(q1a, u2h2(A0.z), 0.f));
            float p10 = dot2acc(q0b, u2h2(A1.y), dot2acc(q0a, u2h2(A1.x), 0.f));
            float p11 = dot2acc(q1b, u2h2(A1.w), dot2acc(q1a, u2h2(A1.z), 0.f));
            p00 = wave16_sum(p00);
            p01 = wave16_sum(p01);
            p10 = wave16_sum(p10);
            p11 = wave16_sum(p11);
            if (base + 1 > last) { p10 = -1e30f; p11 = -1e30f; }

            float2 c00 = h2f(B0.x), c01 = h2f(B0.y), c02 = h2f(B0.z), c03 = h2f(B0.w);
            float2 c10 = h2f(B1.x), c11 = h2f(B1.y), c12 = h2f(B1.z), c13 = h2f(B1.w);
            float v00[4] = {c00.x, c00.y, c01.x, c01.y};
            float v01[4] = {c02.x, c02.y, c03.x, c03.y};
            float v10[4] = {c10.x, c10.y, c11.x, c11.y};
            float v11[4] = {c12.x, c12.y, c13.x, c13.y};

            {
                float nm = fmaxf(m0, fmaxf(p00, p10));
                float f = exp2fast(m0 - nm);
                float e0 = exp2fast(p00 - nm);
                float e1 = exp2fast(p10 - nm);
                l0 = l0 * f + e0 + e1;
                #pragma unroll
                for (int r = 0; r < 4; ++r)
                    acc0[r] = acc0[r] * f + e0 * v00[r] + e1 * v10[r];
                m0 = nm;
            }
            {
                float nm = fmaxf(m1, fmaxf(p01, p11));
                float f = exp2fast(m1 - nm);
                float e0 = exp2fast(p01 - nm);
                float e1 = exp2fast(p11 - nm);
                l1 = l1 * f + e0 + e1;
                #pragma unroll
                for (int r = 0; r < 4; ++r)
                    acc1[r] = acc1[r] * f + e0 * v01[r] + e1 * v11[r];
                m1 = nm;
            }
        }
        // butterfly-merge the 4 slot states (masks 16, 32)
        #pragma unroll
        for (int mask = 16; mask <= 32; mask <<= 1) {
            {
                float mo = __shfl_xor(m0, mask);
                float lo = __shfl_xor(l0, mask);
                float ao[4];
                #pragma unroll
                for (int r = 0; r < 4; ++r) ao[r] = __shfl_xor(acc0[r], mask);
                float nm = fmaxf(m0, mo);
                float fa = exp2fast(m0 - nm);
                float fb = exp2fast(mo - nm);
                l0 = l0 * fa + lo * fb;
                #pragma unroll
                for (int r = 0; r < 4; ++r) acc0[r] = acc0[r] * fa + ao[r] * fb;
                m0 = nm;
            }
            {
                float mo = __shfl_xor(m1, mask);
                float lo = __shfl_xor(l1, mask);
                float ao[4];
                #pragma unroll
                for (int r = 0; r < 4; ++r) ao[r] = __shfl_xor(acc1[r], mask);
                float nm = fmaxf(m1, mo);
                float fa = exp2fast(m1 - nm);
                float fb = exp2fast(mo - nm);
                l1 = l1 * fa + lo * fb;
                #pragma unroll
                for (int r = 0; r < 4; ++r) acc1[r] = acc1[r] * fa + ao[r] * fb;
                m1 = nm;
            }
        }
        float i0 = 1.f / (l0 + 1e-16f);
        float i1 = 1.f / (l1 + 1e-16f);
        uint2 sku = *(const uint2*)(skiph + (size_t)node * 64 + j * 4);
        float2 s0f = h2f(sku.x), s1f = h2f(sku.y);
        float ska[4] = {s0f.x, s0f.y, s1f.x, s1f.y};
        float val[4];
        #pragma unroll
        for (int r = 0; r < 4; ++r) {
            float o = 0.5f * (acc0[r] * i0 + acc1[r] * i1) + ska[r];
            val[r] = fmaxf(o, 0.f);
        }
        if (do_ln) {
            float s = val[0] + val[1] + val[2] + val[3];
            s = wave16_sum(s);
            float mu = s * (1.f / 64.f);
            float ss = 0.f;
            #pragma unroll
            for (int r = 0; r < 4; ++r) { float d = val[r] - mu; ss += d * d; }
            ss = wave16_sum(ss);
            float rstd = rsqrtf(ss * (1.f / 64.f) + 1e-5f);
            float4 g4 = *(const float4*)(gamma + j * 4);
            float4 b4 = *(const float4*)(beta + j * 4);
            float ga[4] = {g4.x, g4.y, g4.z, g4.w};
            float ba[4] = {b4.x, b4.y, b4.z, b4.w};
            #pragma unroll
            for (int r = 0; r < 4; ++r) val[r] = (val[r] - mu) * rstd * ga[r] + ba[r];
        }
        if (slot == 0) {
            ushort4 o = make_ushort4(f2us(val[0]), f2us(val[1]), f2us(val[2]), f2us(val[3]));
            *(ushort4*)(hout + (size_t)node * 64 + j * 4) = o;
        }
    }
}

// ---------------- fused pool + final projection (batch is sorted) ----------------
__device__ __forceinline__ int lbound(const int* __restrict__ a, int n, int key) {
    int lo = 0, hi = n;
    while (lo < hi) {
        int mid = (lo + hi) >> 1;
        if (a[mid] < key) lo = mid + 1; else hi = mid;
    }
    return lo;
}

__global__ __launch_bounds__(256) void pool_final_kernel(
    const unsigned short* __restrict__ h, const int* __restrict__ batch,
    const float* __restrict__ Wout, const float* __restrict__ bout,
    float* __restrict__ out) {
    __shared__ int sh_lo, sh_hi;
    __shared__ float part[4][64];
    int g = blockIdx.x;
    int t = threadIdx.x;
    if (t == 0) {
        sh_lo = lbound(batch, NN, g);
        sh_hi = lbound(batch, NN, g + 1);
    }
    __syncthreads();
    int lo = sh_lo, hi = sh_hi;
    int c = t & 63, w = t >> 6;
    float s = 0.f;
    for (int n = lo + w; n < hi; n += 4) s += us2f(h[(size_t)n * 64 + c]);
    part[w][c] = s;
    __syncthreads();
    if (t < 64) {
        float tot = part[0][t] + part[1][t] + part[2][t] + part[3][t];
        float cnt = (float)(hi - lo);
        float val = tot / fmaxf(cnt, 1.f) * Wout[t];
        #pragma unroll
        for (int mk = 1; mk < 64; mk <<= 1) val += __shfl_xor(val, mk);
        if (t == 0) out[g] = val + bout[0];
    }
}

extern "C" void kernel_launch(void* const* d_in, const int* in_sizes, int n_in,
                              void* d_out, int out_size, void* d_ws, size_t ws_size,
                              hipStream_t stream) {
    const float* x    = (const float*)d_in[0];
    const int*   ei   = (const int*)d_in[1];
    const int*   batch= (const int*)d_in[2];
    const float* Wq   = (const float*)d_in[4];
    const float* bq   = (const float*)d_in[5];
    const float* Wk   = (const float*)d_in[6];
    const float* bk   = (const float*)d_in[7];
    const float* Wv   = (const float*)d_in[8];
    const float* bv   = (const float*)d_in[9];
    const float* Ws   = (const float*)d_in[10];
    const float* bs   = (const float*)d_in[11];
    const float* lng  = (const float*)d_in[12];
    const float* lnb  = (const float*)d_in[13];
    const float* Wout = (const float*)d_in[14];
    const float* bout = (const float*)d_in[15];
    float* out = (float*)d_out;

    unsigned short* qh  = (unsigned short*)d_ws;
    unsigned short* kvh = qh + (size_t)NN * 128;
    unsigned short* skiph = kvh + (size_t)NN * 256;
    unsigned short* xh0 = skiph + (size_t)NN * 64;
    unsigned short* xh1 = xh0 + (size_t)NN * 64;
    unsigned short* wt  = xh1 + (size_t)NN * 64;
    int* deg    = (int*)(wt + 3 * WT_LSTRIDE + 64);  // +64 us: alignment slack
    int* ctrs   = deg + NN;       // 4 work-stealing counters (zeroed with deg)
    int* rowst  = ctrs + 4;
    int* cursor = rowst + NN;
    int* bsum   = cursor + NN;
    unsigned short* esrc = (unsigned short*)(bsum + 256);

    hipMemsetAsync(deg, 0, (NN + 4) * sizeof(int), stream);

    const int NB = (NN + 255) / 256;  // 196
    // fused: x-cast || W-pack || degree count
    prep_kernel<<<XCAST_BLKS + 21 + DEG_BLKS, 256, 0, stream>>>(
        x, xh0, Wq, Wk, Wv, Ws, wt, ei, deg);
    scan1<<<NB, 256, 0, stream>>>(deg, rowst, bsum);
    scan2<<<1, 256, 0, stream>>>(bsum, NB);
    scan3<<<NB, 256, 0, stream>>>(rowst, deg, bsum, cursor);

    unsigned short* hin = xh0;
    unsigned short* houts[3] = {xh1, xh0, xh1};
    for (int l = 0; l < 3; ++l) {
        // layer 0: gemm || CSR fill fused; layers 1,2: gemm only
        int grid = (l == 0) ? (GEMM_GRID_C + DEG_BLKS) : GEMM_GRID_C;
        gemm_fill<<<grid, 256, 0, stream>>>(hin, wt + (size_t)l * WT_LSTRIDE,
            bq + (size_t)l * 128, bk + (size_t)l * 128, bv + (size_t)l * 128,
            bs + (size_t)l * 64, qh, kvh, skiph, ei, cursor, esrc);
        int do_ln = (l < 2) ? 1 : 0;
        agg_kernel<<<2048, 256, 0, stream>>>(qh, kvh, skiph, rowst, deg, esrc,
                                             lng + (size_t)(do_ln ? l : 0) * 64,
                                             lnb + (size_t)(do_ln ? l : 0) * 64,
                                             houts[l], do_ln, ctrs + l);
        hin = houts[l];
    }
    pool_final_kernel<<<GG, 256, 0, stream>>>(hin, batch, Wout, bout, out);
}

// Round 15
// 408.972 us; speedup vs baseline: 5.4856x; 5.4856x over previous
//
#include <hip/hip_runtime.h>
#include <hip/hip_fp16.h>
#include <math.h>

#define NN 50000
#define EE 800000
#define GG 512

typedef _Float16 f16x8 __attribute__((ext_vector_type(8)));
typedef _Float16 f16x2 __attribute__((ext_vector_type(2)));
typedef float f32x4 __attribute__((ext_vector_type(4)));

#if defined(__has_builtin)
#if __has_builtin(__builtin_amdgcn_fdot2)
#define HAS_FDOT2 1
#endif
#endif

// fold 1/sqrt(64) * log2(e) into q so scores are in log2 domain
#define QSCALE 0.1803368801111244f

__device__ __forceinline__ float wave16_sum(float p) {
    p += __shfl_xor(p, 1);
    p += __shfl_xor(p, 2);
    p += __shfl_xor(p, 4);
    p += __shfl_xor(p, 8);
    return p;
}
__device__ __forceinline__ float2 h2f(unsigned int u) {
    __half2 h = *reinterpret_cast<__half2*>(&u);
    return __half22float2(h);
}
__device__ __forceinline__ unsigned short f2us(float x) {
    return __half_as_ushort(__float2half(x));
}
__device__ __forceinline__ float us2f(unsigned short u) {
    return __half2float(__ushort_as_half(u));
}
__device__ __forceinline__ f16x2 u2h2(unsigned int u) {
    union { unsigned int u; f16x2 h; } x; x.u = u; return x.h;
}
__device__ __forceinline__ float dot2acc(f16x2 a, f16x2 b, float c) {
#ifdef HAS_FDOT2
    return __builtin_amdgcn_fdot2(a, b, c, false);
#else
    return c + (float)a[0] * (float)b[0] + (float)a[1] * (float)b[1];
#endif
}
__device__ __forceinline__ float exp2fast(float x) {
    return __builtin_amdgcn_exp2f(x);
}

// ---------------- scans (CSR build) ----------------
__global__ void scan1(const int* __restrict__ deg, int* __restrict__ incl, int* __restrict__ bsum) {
    __shared__ int sh[256];
    int t = threadIdx.x;
    int n = blockIdx.x * 256 + t;
    int vv = (n < NN) ? deg[n] : 0;
    sh[t] = vv; __syncthreads();
    for (int off = 1; off < 256; off <<= 1) {
        int u = (t >= off) ? sh[t - off] : 0;
        __syncthreads();
        sh[t] += u;
        __syncthreads();
    }
    if (n < NN) incl[n] = sh[t];
    if (t == 255) bsum[blockIdx.x] = sh[255];
}

__global__ void scan2(int* __restrict__ bsum, int nblk) {
    __shared__ int sh[256];
    int t = threadIdx.x;
    int vv = (t < nblk) ? bsum[t] : 0;
    sh[t] = vv; __syncthreads();
    for (int off = 1; off < 256; off <<= 1) {
        int u = (t >= off) ? sh[t - off] : 0;
        __syncthreads();
        sh[t] += u;
        __syncthreads();
    }
    bsum[t] = sh[t];
}

__global__ void scan3(int* __restrict__ rowst, const int* __restrict__ deg,
                      const int* __restrict__ bsum, int* __restrict__ cursor) {
    int n = blockIdx.x * 256 + threadIdx.x;
    if (n >= NN) return;
    int off = (blockIdx.x > 0) ? bsum[blockIdx.x - 1] : 0;
    int excl = rowst[n] - deg[n] + off;
    rowst[n] = excl;
    cursor[n] = excl;
}

// ---------------- fused prep: x-cast || W-pack || degree count ----------------
// wt layout per layer: [448][64] fp16, wt[c][k] = W[k][c]; c: 0..127 q, 128..255 k, 256..383 v, 384..447 skip
#define WT_LSTRIDE (448 * 64)
#define XCAST_BLKS 3125   // NN*16/256
#define DEG_BLKS 3125     // EE/256
__global__ void prep_kernel(const float* __restrict__ x, unsigned short* __restrict__ xh,
                            const float* __restrict__ Wq, const float* __restrict__ Wk,
                            const float* __restrict__ Wv, const float* __restrict__ Ws,
                            unsigned short* __restrict__ wt,
                            const int* __restrict__ ei, int* __restrict__ deg) {
    __shared__ float lds_t[64][65];
    int b = blockIdx.x;
    if (b < XCAST_BLKS) {
        int i = b * 256 + threadIdx.x;
        float4 v = *(const float4*)(x + (size_t)i * 4);
        ushort4 o = make_ushort4(f2us(v.x), f2us(v.y), f2us(v.z), f2us(v.w));
        *(ushort4*)(xh + (size_t)i * 4) = o;
        return;
    }
    if (b < XCAST_BLKS + 21) {
        int tile = b - XCAST_BLKS;  // 0..20
        int l = tile / 7, ct = tile % 7;
        int c0 = ct * 64;
        int t = threadIdx.x;
        #pragma unroll
        for (int r = 0; r < 16; ++r) {
            int idx = r * 256 + t;
            int kk = idx >> 6, cc = idx & 63;
            int c = c0 + cc;
            float val;
            if (c < 384) {
                int m = c >> 7, col = c & 127;
                const float* W = (m == 0) ? Wq : ((m == 1) ? Wk : Wv);
                val = W[(size_t)l * 8192 + kk * 128 + col];
            } else {
                val = Ws[(size_t)l * 4096 + kk * 64 + (c - 384)];
            }
            lds_t[cc][kk] = val;
        }
        __syncthreads();
        #pragma unroll
        for (int r = 0; r < 16; ++r) {
            int idx = r * 256 + t;
            int cc = idx >> 6, kk = idx & 63;
            wt[((size_t)l * 448 + c0 + cc) * 64 + kk] = f2us(lds_t[cc][kk]);
        }
        return;
    }
    int e = (b - XCAST_BLKS - 21) * 256 + threadIdx.x;
    if (e < EE) atomicAdd(&deg[ei[EE + e]], 1);
}

// ---------------- MFMA GEMM (LDS-staged coalesced epilogue) || CSR fill ----------------
// kvh row layout (interleaved for agg): group j (0..15) holds halves [j*16, j*16+16):
//   k0[j*4..+3], k1[...], v0[...], v1[...]
#define GEMM_GRID_C 1563  // ceil(NN/32)
__global__ __launch_bounds__(256) void gemm_fill(
    const unsigned short* __restrict__ xh,
    const unsigned short* __restrict__ wt,
    const float* __restrict__ bq, const float* __restrict__ bk,
    const float* __restrict__ bv, const float* __restrict__ bsk,
    unsigned short* __restrict__ qh, unsigned short* __restrict__ kvh,
    unsigned short* __restrict__ skiph,
    const int* __restrict__ ei, int* __restrict__ cursor,
    unsigned short* __restrict__ esrc) {
    __shared__ __align__(16) unsigned short lds_q[32 * 128];
    __shared__ __align__(16) unsigned short lds_kv[32 * 256];
    __shared__ __align__(16) unsigned short lds_sk[32 * 64];
    if (blockIdx.x >= GEMM_GRID_C) {
        // CSR fill branch (only present in layer-0 launch)
        int e = (blockIdx.x - GEMM_GRID_C) * 256 + threadIdx.x;
        if (e < EE) {
            int s = ei[e], d = ei[EE + e];
            int pos = atomicAdd(&cursor[d], 1);
            esrc[pos] = (unsigned short)s;
        }
        return;
    }
    int t = threadIdx.x;
    int wave = t >> 6, lane = t & 63;
    int li = lane & 15, lh = lane >> 4;
    int brow = blockIdx.x * 32;
    int row0 = brow + (wave & 1) * 16;
    int ctbase = (wave >> 1) * 14;

    int arow = min(row0 + li, NN - 1);
    const unsigned short* ap = xh + (size_t)arow * 64 + lh * 8;
    f16x8 a0 = *(const f16x8*)(ap);
    f16x8 a1 = *(const f16x8*)(ap + 32);

    int rl0 = (wave & 1) * 16 + lh * 4;

    #pragma unroll 2
    for (int tt = 0; tt < 14; ++tt) {
        int c = (ctbase + tt) * 16 + li;
        const unsigned short* bp = wt + (size_t)c * 64 + lh * 8;
        f16x8 b0 = *(const f16x8*)(bp);
        f16x8 b1 = *(const f16x8*)(bp + 32);
        f32x4 d = {0.f, 0.f, 0.f, 0.f};
        d = __builtin_amdgcn_mfma_f32_16x16x32_f16(a0, b0, d, 0, 0, 0);
        d = __builtin_amdgcn_mfma_f32_16x16x32_f16(a1, b1, d, 0, 0, 0);
        if (c < 128) {
            float bias = bq[c];
            #pragma unroll
            for (int e = 0; e < 4; ++e)
                lds_q[(rl0 + e) * 128 + c] = f2us((d[e] + bias) * QSCALE);
        } else if (c < 256) {
            int ch = c - 128;
            float bias = bk[ch];
            int off = (ch < 64) ? ((ch >> 2) * 16 + (ch & 3))
                                : (((ch - 64) >> 2) * 16 + 4 + (ch & 3));
            #pragma unroll
            for (int e = 0; e < 4; ++e)
                lds_kv[(rl0 + e) * 256 + off] = f2us(d[e] + bias);
        } else if (c < 384) {
            int ch = c - 256;
            float bias = bv[ch];
            int off = 8 + ((ch < 64) ? ((ch >> 2) * 16 + (ch & 3))
                                     : (((ch - 64) >> 2) * 16 + 4 + (ch & 3)));
            #pragma unroll
            for (int e = 0; e < 4; ++e)
                lds_kv[(rl0 + e) * 256 + off] = f2us(d[e] + bias);
        } else {
            int ch = c - 384;
            float bias = bsk[ch];
            #pragma unroll
            for (int e = 0; e < 4; ++e)
                lds_sk[(rl0 + e) * 64 + ch] = f2us(d[e] + bias);
        }
    }
    __syncthreads();
    // coalesced write-out: rows brow..brow+31 contiguous in each output array
    #pragma unroll
    for (int i = t; i < 512; i += 256) {          // q: 32 rows x 128h = 512 x 16B
        int r = i >> 4, gr = brow + r;
        if (gr < NN)
            *(uint4*)(qh + (size_t)gr * 128 + (i & 15) * 8) = ((const uint4*)lds_q)[i];
    }
    #pragma unroll
    for (int i = t; i < 1024; i += 256) {         // kv: 32 rows x 256h = 1024 x 16B
        int r = i >> 5, gr = brow + r;
        if (gr < NN)
            *(uint4*)(kvh + (size_t)gr * 256 + (i & 31) * 8) = ((const uint4*)lds_kv)[i];
    }
    {
        int i = t;                                 // skip: 32 rows x 64h = 256 x 16B
        int r = i >> 3, gr = brow + r;
        if (i < 256 && gr < NN)
            *(uint4*)(skiph + (size_t)gr * 64 + (i & 7) * 8) = ((const uint4*)lds_sk)[i];
    }
}

// ---------------- per-node attention aggregation (static 4 nodes/block, round-13) ----------------
__global__ __launch_bounds__(256) void agg_kernel(
    const unsigned short* __restrict__ qh, const unsigned short* __restrict__ kvh,
    const unsigned short* __restrict__ skiph,
    const int* __restrict__ rowst, const int* __restrict__ deg,
    const unsigned short* __restrict__ esrc, const float* __restrict__ gamma,
    const float* __restrict__ beta, unsigned short* __restrict__ hout, int do_ln) {
    int wave = threadIdx.x >> 6;
    int lane = threadIdx.x & 63;
    int node = blockIdx.x * 4 + wave;
    if (node >= NN) return;
    int j = lane & 15;
    int slot = lane >> 4;

    // q (pre-scaled by 0.125*log2e): head0 dims j*4..+3, head1 at +64
    uint2 qu0 = *(const uint2*)(qh + (size_t)node * 128 + j * 4);
    uint2 qu1 = *(const uint2*)(qh + (size_t)node * 128 + 64 + j * 4);
    f16x2 q0a = u2h2(qu0.x), q0b = u2h2(qu0.y);
    f16x2 q1a = u2h2(qu1.x), q1b = u2h2(qu1.y);

    float m0 = -1e30f, m1 = -1e30f;
    float l0 = 0.f, l1 = 0.f;
    float acc0[4] = {0.f, 0.f, 0.f, 0.f};
    float acc1[4] = {0.f, 0.f, 0.f, 0.f};

    int st = rowst[node];
    int dg = deg[node];
    int last = dg - 1;
    for (int base = slot * 2; base < dg; base += 8) {
        int s0 = (int)esrc[st + min(base + 0, last)];
        int s1 = (int)esrc[st + min(base + 1, last)];
        const unsigned short* b0 = kvh + (size_t)s0 * 256 + j * 16;
        const unsigned short* b1 = kvh + (size_t)s1 * 256 + j * 16;
        uint4 A0 = *(const uint4*)(b0);       // k0[4],k1[4]
        uint4 B0 = *(const uint4*)(b0 + 8);   // v0[4],v1[4]
        uint4 A1 = *(const uint4*)(b1);
        uint4 B1 = *(const uint4*)(b1 + 8);

        // scores via packed fp16 dot (log2 domain)
        float p00 = dot2acc(q0b, u2h2(A0.y), dot2acc(q0a, u2h2(A0.x), 0.f));
        float p01 = dot2acc(q1b, u2h2(A0.w), dot2acc(q1a, u2h2(A0.z), 0.f));
        float p10 = dot2acc(q0b, u2h2(A1.y), dot2acc(q0a, u2h2(A1.x), 0.f));
        float p11 = dot2acc(q1b, u2h2(A1.w), dot2acc(q1a, u2h2(A1.z), 0.f));
        p00 = wave16_sum(p00);
        p01 = wave16_sum(p01);
        p10 = wave16_sum(p10);
        p11 = wave16_sum(p11);
        if (base + 1 > last) { p10 = -1e30f; p11 = -1e30f; }

        float2 c00 = h2f(B0.x), c01 = h2f(B0.y), c02 = h2f(B0.z), c03 = h2f(B0.w);
        float2 c10 = h2f(B1.x), c11 = h2f(B1.y), c12 = h2f(B1.z), c13 = h2f(B1.w);
        float v00[4] = {c00.x, c00.y, c01.x, c01.y};
        float v01[4] = {c02.x, c02.y, c03.x, c03.y};
        float v10[4] = {c10.x, c10.y, c11.x, c11.y};
        float v11[4] = {c12.x, c12.y, c13.x, c13.y};

        {
            float nm = fmaxf(m0, fmaxf(p00, p10));
            float f = exp2fast(m0 - nm);
            float e0 = exp2fast(p00 - nm);
            float e1 = exp2fast(p10 - nm);
            l0 = l0 * f + e0 + e1;
            #pragma unroll
            for (int r = 0; r < 4; ++r)
                acc0[r] = acc0[r] * f + e0 * v00[r] + e1 * v10[r];
            m0 = nm;
        }
        {
            float nm = fmaxf(m1, fmaxf(p01, p11));
            float f = exp2fast(m1 - nm);
            float e0 = exp2fast(p01 - nm);
            float e1 = exp2fast(p11 - nm);
            l1 = l1 * f + e0 + e1;
            #pragma unroll
            for (int r = 0; r < 4; ++r)
                acc1[r] = acc1[r] * f + e0 * v01[r] + e1 * v11[r];
            m1 = nm;
        }
    }
    // butterfly-merge the 4 slot states (masks 16, 32)
    #pragma unroll
    for (int mask = 16; mask <= 32; mask <<= 1) {
        {
            float mo = __shfl_xor(m0, mask);
            float lo = __shfl_xor(l0, mask);
            float ao[4];
            #pragma unroll
            for (int r = 0; r < 4; ++r) ao[r] = __shfl_xor(acc0[r], mask);
            float nm = fmaxf(m0, mo);
            float fa = exp2fast(m0 - nm);
            float fb = exp2fast(mo - nm);
            l0 = l0 * fa + lo * fb;
            #pragma unroll
            for (int r = 0; r < 4; ++r) acc0[r] = acc0[r] * fa + ao[r] * fb;
            m0 = nm;
        }
        {
            float mo = __shfl_xor(m1, mask);
            float lo = __shfl_xor(l1, mask);
            float ao[4];
            #pragma unroll
            for (int r = 0; r < 4; ++r) ao[r] = __shfl_xor(acc1[r], mask);
            float nm = fmaxf(m1, mo);
            float fa = exp2fast(m1 - nm);
            float fb = exp2fast(mo - nm);
            l1 = l1 * fa + lo * fb;
            #pragma unroll
            for (int r = 0; r < 4; ++r) acc1[r] = acc1[r] * fa + ao[r] * fb;
            m1 = nm;
        }
    }
    float i0 = 1.f / (l0 + 1e-16f);
    float i1 = 1.f / (l1 + 1e-16f);
    uint2 sku = *(const uint2*)(skiph + (size_t)node * 64 + j * 4);
    float2 s0f = h2f(sku.x), s1f = h2f(sku.y);
    float ska[4] = {s0f.x, s0f.y, s1f.x, s1f.y};
    float val[4];
    #pragma unroll
    for (int r = 0; r < 4; ++r) {
        float o = 0.5f * (acc0[r] * i0 + acc1[r] * i1) + ska[r];
        val[r] = fmaxf(o, 0.f);
    }
    if (do_ln) {
        float s = val[0] + val[1] + val[2] + val[3];
        s = wave16_sum(s);
        float mu = s * (1.f / 64.f);
        float ss = 0.f;
        #pragma unroll
        for (int r = 0; r < 4; ++r) { float d = val[r] - mu; ss += d * d; }
        ss = wave16_sum(ss);
        float rstd = rsqrtf(ss * (1.f / 64.f) + 1e-5f);
        float4 g4 = *(const float4*)(gamma + j * 4);
        float4 b4 = *(const float4*)(beta + j * 4);
        float ga[4] = {g4.x, g4.y, g4.z, g4.w};
        float ba[4] = {b4.x, b4.y, b4.z, b4.w};
        #pragma unroll
        for (int r = 0; r < 4; ++r) val[r] = (val[r] - mu) * rstd * ga[r] + ba[r];
    }
    if (slot == 0) {
        ushort4 o = make_ushort4(f2us(val[0]), f2us(val[1]), f2us(val[2]), f2us(val[3]));
        *(ushort4*)(hout + (size_t)node * 64 + j * 4) = o;
    }
}

// ---------------- fused pool + final projection (batch is sorted) ----------------
__device__ __forceinline__ int lbound(const int* __restrict__ a, int n, int key) {
    int lo = 0, hi = n;
    while (lo < hi) {
        int mid = (lo + hi) >> 1;
        if (a[mid] < key) lo = mid + 1; else hi = mid;
    }
    return lo;
}

__global__ __launch_bounds__(256) void pool_final_kernel(
    const unsigned short* __restrict__ h, const int* __restrict__ batch,
    const float* __restrict__ Wout, const float* __restrict__ bout,
    float* __restrict__ out) {
    __shared__ int sh_lo, sh_hi;
    __shared__ float part[4][64];
    int g = blockIdx.x;
    int t = threadIdx.x;
    if (t == 0) {
        sh_lo = lbound(batch, NN, g);
        sh_hi = lbound(batch, NN, g + 1);
    }
    __syncthreads();
    int lo = sh_lo, hi = sh_hi;
    int c = t & 63, w = t >> 6;
    float s = 0.f;
    for (int n = lo + w; n < hi; n += 4) s += us2f(h[(size_t)n * 64 + c]);
    part[w][c] = s;
    __syncthreads();
    if (t < 64) {
        float tot = part[0][t] + part[1][t] + part[2][t] + part[3][t];
        float cnt = (float)(hi - lo);
        float val = tot / fmaxf(cnt, 1.f) * Wout[t];
        #pragma unroll
        for (int mk = 1; mk < 64; mk <<= 1) val += __shfl_xor(val, mk);
        if (t == 0) out[g] = val + bout[0];
    }
}

extern "C" void kernel_launch(void* const* d_in, const int* in_sizes, int n_in,
                              void* d_out, int out_size, void* d_ws, size_t ws_size,
                              hipStream_t stream) {
    const float* x    = (const float*)d_in[0];
    const int*   ei   = (const int*)d_in[1];
    const int*   batch= (const int*)d_in[2];
    const float* Wq   = (const float*)d_in[4];
    const float* bq   = (const float*)d_in[5];
    const float* Wk   = (const float*)d_in[6];
    const float* bk   = (const float*)d_in[7];
    const float* Wv   = (const float*)d_in[8];
    const float* bv   = (const float*)d_in[9];
    const float* Ws   = (const float*)d_in[10];
    const float* bs   = (const float*)d_in[11];
    const float* lng  = (const float*)d_in[12];
    const float* lnb  = (const float*)d_in[13];
    const float* Wout = (const float*)d_in[14];
    const float* bout = (const float*)d_in[15];
    float* out = (float*)d_out;

    unsigned short* qh  = (unsigned short*)d_ws;
    unsigned short* kvh = qh + (size_t)NN * 128;
    unsigned short* skiph = kvh + (size_t)NN * 256;
    unsigned short* xh0 = skiph + (size_t)NN * 64;
    unsigned short* xh1 = xh0 + (size_t)NN * 64;
    unsigned short* wt  = xh1 + (size_t)NN * 64;
    int* deg    = (int*)(wt + 3 * WT_LSTRIDE + 64);  // +64 us: alignment slack
    int* rowst  = deg + NN;
    int* cursor = rowst + NN;
    int* bsum   = cursor + NN;
    unsigned short* esrc = (unsigned short*)(bsum + 256);

    hipMemsetAsync(deg, 0, NN * sizeof(int), stream);

    const int NB = (NN + 255) / 256;  // 196
    // fused: x-cast || W-pack || degree count
    prep_kernel<<<XCAST_BLKS + 21 + DEG_BLKS, 256, 0, stream>>>(
        x, xh0, Wq, Wk, Wv, Ws, wt, ei, deg);
    scan1<<<NB, 256, 0, stream>>>(deg, rowst, bsum);
    scan2<<<1, 256, 0, stream>>>(bsum, NB);
    scan3<<<NB, 256, 0, stream>>>(rowst, deg, bsum, cursor);

    unsigned short* hin = xh0;
    unsigned short* houts[3] = {xh1, xh0, xh1};
    for (int l = 0; l < 3; ++l) {
        // layer 0: gemm || CSR fill fused; layers 1,2: gemm only
        int grid = (l == 0) ? (GEMM_GRID_C + DEG_BLKS) : GEMM_GRID_C;
        gemm_fill<<<grid, 256, 0, stream>>>(hin, wt + (size_t)l * WT_LSTRIDE,
            bq + (size_t)l * 128, bk + (size_t)l * 128, bv + (size_t)l * 128,
            bs + (size_t)l * 64, qh, kvh, skiph, ei, cursor, esrc);
        int do_ln = (l < 2) ? 1 : 0;
        agg_kernel<<<(NN + 3) / 4, 256, 0, stream>>>(qh, kvh, skiph, rowst, deg, esrc,
                                                     lng + (size_t)(do_ln ? l : 0) * 64,
                                                     lnb + (size_t)(do_ln ? l : 0) * 64,
                                                     houts[l], do_ln);
        hin = houts[l];
    }
    pool_final_kernel<<<GG, 256, 0, stream>>>(hin, batch, Wout, bout, out);
}

// Round 16
// 402.225 us; speedup vs baseline: 5.5776x; 1.0168x over previous
//
#include <hip/hip_runtime.h>
#include <hip/hip_fp16.h>
#include <math.h>

#define NN 50000
#define EE 800000
#define GG 512

typedef _Float16 f16x8 __attribute__((ext_vector_type(8)));
typedef _Float16 f16x2 __attribute__((ext_vector_type(2)));
typedef float f32x4 __attribute__((ext_vector_type(4)));

#if defined(__has_builtin)
#if __has_builtin(__builtin_amdgcn_fdot2)
#define HAS_FDOT2 1
#endif
#endif

// fold 1/sqrt(64) * log2(e) into q so scores are in log2 domain
#define QSCALE 0.1803368801111244f

__device__ __forceinline__ float wave16_sum(float p) {
    p += __shfl_xor(p, 1);
    p += __shfl_xor(p, 2);
    p += __shfl_xor(p, 4);
    p += __shfl_xor(p, 8);
    return p;
}
__device__ __forceinline__ float2 h2f(unsigned int u) {
    __half2 h = *reinterpret_cast<__half2*>(&u);
    return __half22float2(h);
}
__device__ __forceinline__ unsigned short f2us(float x) {
    return __half_as_ushort(__float2half(x));
}
__device__ __forceinline__ float us2f(unsigned short u) {
    return __half2float(__ushort_as_half(u));
}
__device__ __forceinline__ f16x2 u2h2(unsigned int u) {
    union { unsigned int u; f16x2 h; } x; x.u = u; return x.h;
}
__device__ __forceinline__ float dot2acc(f16x2 a, f16x2 b, float c) {
#ifdef HAS_FDOT2
    return __builtin_amdgcn_fdot2(a, b, c, false);
#else
    return c + (float)a[0] * (float)b[0] + (float)a[1] * (float)b[1];
#endif
}
__device__ __forceinline__ float exp2fast(float x) {
    return __builtin_amdgcn_exp2f(x);
}

// ---------------- scans (CSR build) ----------------
__global__ void scan1(const int* __restrict__ deg, int* __restrict__ incl, int* __restrict__ bsum) {
    __shared__ int sh[256];
    int t = threadIdx.x;
    int n = blockIdx.x * 256 + t;
    int vv = (n < NN) ? deg[n] : 0;
    sh[t] = vv; __syncthreads();
    for (int off = 1; off < 256; off <<= 1) {
        int u = (t >= off) ? sh[t - off] : 0;
        __syncthreads();
        sh[t] += u;
        __syncthreads();
    }
    if (n < NN) incl[n] = sh[t];
    if (t == 255) bsum[blockIdx.x] = sh[255];
}

__global__ void scan2(int* __restrict__ bsum, int nblk) {
    __shared__ int sh[256];
    int t = threadIdx.x;
    int vv = (t < nblk) ? bsum[t] : 0;
    sh[t] = vv; __syncthreads();
    for (int off = 1; off < 256; off <<= 1) {
        int u = (t >= off) ? sh[t - off] : 0;
        __syncthreads();
        sh[t] += u;
        __syncthreads();
    }
    bsum[t] = sh[t];
}

__global__ void scan3(int* __restrict__ rowst, const int* __restrict__ deg,
                      const int* __restrict__ bsum, int* __restrict__ cursor) {
    int n = blockIdx.x * 256 + threadIdx.x;
    if (n >= NN) return;
    int off = (blockIdx.x > 0) ? bsum[blockIdx.x - 1] : 0;
    int excl = rowst[n] - deg[n] + off;
    rowst[n] = excl;
    cursor[n] = excl;
}

// ---------------- CSR fill (separate: no LDS -> full occupancy; nt store) ----------------
__global__ void fill_kernel(const int* __restrict__ ei, int* __restrict__ cursor,
                            unsigned short* __restrict__ esrc) {
    int e = blockIdx.x * 256 + threadIdx.x;
    if (e < EE) {
        int s = ei[e], d = ei[EE + e];
        int pos = atomicAdd(&cursor[d], 1);
        __builtin_nontemporal_store((unsigned short)s, &esrc[pos]);
    }
}

// ---------------- fused prep: x-cast || W-pack || degree count ----------------
// wt layout per layer: [448][64] fp16, wt[c][k] = W[k][c]; c: 0..127 q, 128..255 k, 256..383 v, 384..447 skip
#define WT_LSTRIDE (448 * 64)
#define XCAST_BLKS 3125   // NN*16/256
#define DEG_BLKS 3125     // EE/256
__global__ void prep_kernel(const float* __restrict__ x, unsigned short* __restrict__ xh,
                            const float* __restrict__ Wq, const float* __restrict__ Wk,
                            const float* __restrict__ Wv, const float* __restrict__ Ws,
                            unsigned short* __restrict__ wt,
                            const int* __restrict__ ei, int* __restrict__ deg) {
    __shared__ float lds_t[64][65];
    int b = blockIdx.x;
    if (b < XCAST_BLKS) {
        int i = b * 256 + threadIdx.x;
        float4 v = *(const float4*)(x + (size_t)i * 4);
        ushort4 o = make_ushort4(f2us(v.x), f2us(v.y), f2us(v.z), f2us(v.w));
        *(ushort4*)(xh + (size_t)i * 4) = o;
        return;
    }
    if (b < XCAST_BLKS + 21) {
        int tile = b - XCAST_BLKS;  // 0..20
        int l = tile / 7, ct = tile % 7;
        int c0 = ct * 64;
        int t = threadIdx.x;
        #pragma unroll
        for (int r = 0; r < 16; ++r) {
            int idx = r * 256 + t;
            int kk = idx >> 6, cc = idx & 63;
            int c = c0 + cc;
            float val;
            if (c < 384) {
                int m = c >> 7, col = c & 127;
                const float* W = (m == 0) ? Wq : ((m == 1) ? Wk : Wv);
                val = W[(size_t)l * 8192 + kk * 128 + col];
            } else {
                val = Ws[(size_t)l * 4096 + kk * 64 + (c - 384)];
            }
            lds_t[cc][kk] = val;
        }
        __syncthreads();
        #pragma unroll
        for (int r = 0; r < 16; ++r) {
            int idx = r * 256 + t;
            int cc = idx >> 6, kk = idx & 63;
            wt[((size_t)l * 448 + c0 + cc) * 64 + kk] = f2us(lds_t[cc][kk]);
        }
        return;
    }
    int e = (b - XCAST_BLKS - 21) * 256 + threadIdx.x;
    if (e < EE) atomicAdd(&deg[ei[EE + e]], 1);
}

// ---------------- MFMA GEMM (LDS-staged coalesced epilogue) ----------------
// kvh row layout (interleaved for agg): group j (0..15) holds halves [j*16, j*16+16):
//   k0[j*4..+3], k1[...], v0[...], v1[...]
__global__ __launch_bounds__(256) void gemm_mfma(
    const unsigned short* __restrict__ xh,
    const unsigned short* __restrict__ wt,
    const float* __restrict__ bq, const float* __restrict__ bk,
    const float* __restrict__ bv, const float* __restrict__ bsk,
    unsigned short* __restrict__ qh, unsigned short* __restrict__ kvh,
    unsigned short* __restrict__ skiph) {
    __shared__ __align__(16) unsigned short lds_q[32 * 128];
    __shared__ __align__(16) unsigned short lds_kv[32 * 256];
    __shared__ __align__(16) unsigned short lds_sk[32 * 64];
    int t = threadIdx.x;
    int wave = t >> 6, lane = t & 63;
    int li = lane & 15, lh = lane >> 4;
    int brow = blockIdx.x * 32;
    int row0 = brow + (wave & 1) * 16;
    int ctbase = (wave >> 1) * 14;

    int arow = min(row0 + li, NN - 1);
    const unsigned short* ap = xh + (size_t)arow * 64 + lh * 8;
    f16x8 a0 = *(const f16x8*)(ap);
    f16x8 a1 = *(const f16x8*)(ap + 32);

    int rl0 = (wave & 1) * 16 + lh * 4;

    #pragma unroll 2
    for (int tt = 0; tt < 14; ++tt) {
        int c = (ctbase + tt) * 16 + li;
        const unsigned short* bp = wt + (size_t)c * 64 + lh * 8;
        f16x8 b0 = *(const f16x8*)(bp);
        f16x8 b1 = *(const f16x8*)(bp + 32);
        f32x4 d = {0.f, 0.f, 0.f, 0.f};
        d = __builtin_amdgcn_mfma_f32_16x16x32_f16(a0, b0, d, 0, 0, 0);
        d = __builtin_amdgcn_mfma_f32_16x16x32_f16(a1, b1, d, 0, 0, 0);
        if (c < 128) {
            float bias = bq[c];
            #pragma unroll
            for (int e = 0; e < 4; ++e)
                lds_q[(rl0 + e) * 128 + c] = f2us((d[e] + bias) * QSCALE);
        } else if (c < 256) {
            int ch = c - 128;
            float bias = bk[ch];
            int off = (ch < 64) ? ((ch >> 2) * 16 + (ch & 3))
                                : (((ch - 64) >> 2) * 16 + 4 + (ch & 3));
            #pragma unroll
            for (int e = 0; e < 4; ++e)
                lds_kv[(rl0 + e) * 256 + off] = f2us(d[e] + bias);
        } else if (c < 384) {
            int ch = c - 256;
            float bias = bv[ch];
            int off = 8 + ((ch < 64) ? ((ch >> 2) * 16 + (ch & 3))
                                     : (((ch - 64) >> 2) * 16 + 4 + (ch & 3)));
            #pragma unroll
            for (int e = 0; e < 4; ++e)
                lds_kv[(rl0 + e) * 256 + off] = f2us(d[e] + bias);
        } else {
            int ch = c - 384;
            float bias = bsk[ch];
            #pragma unroll
            for (int e = 0; e < 4; ++e)
                lds_sk[(rl0 + e) * 64 + ch] = f2us(d[e] + bias);
        }
    }
    __syncthreads();
    // coalesced write-out: rows brow..brow+31 contiguous in each output array
    #pragma unroll
    for (int i = t; i < 512; i += 256) {          // q: 32 rows x 128h = 512 x 16B
        int r = i >> 4, gr = brow + r;
        if (gr < NN)
            *(uint4*)(qh + (size_t)gr * 128 + (i & 15) * 8) = ((const uint4*)lds_q)[i];
    }
    #pragma unroll
    for (int i = t; i < 1024; i += 256) {         // kv: 32 rows x 256h = 1024 x 16B
        int r = i >> 5, gr = brow + r;
        if (gr < NN)
            *(uint4*)(kvh + (size_t)gr * 256 + (i & 31) * 8) = ((const uint4*)lds_kv)[i];
    }
    {
        int i = t;                                 // skip: 32 rows x 64h = 256 x 16B
        int r = i >> 3, gr = brow + r;
        if (i < 256 && gr < NN)
            *(uint4*)(skiph + (size_t)gr * 64 + (i & 7) * 8) = ((const uint4*)lds_sk)[i];
    }
}

// ---------------- per-node attention aggregation (static 4 nodes/block) ----------------
__global__ __launch_bounds__(256) void agg_kernel(
    const unsigned short* __restrict__ qh, const unsigned short* __restrict__ kvh,
    const unsigned short* __restrict__ skiph,
    const int* __restrict__ rowst, const int* __restrict__ deg,
    const unsigned short* __restrict__ esrc, const float* __restrict__ gamma,
    const float* __restrict__ beta, unsigned short* __restrict__ hout, int do_ln) {
    int wave = threadIdx.x >> 6;
    int lane = threadIdx.x & 63;
    int node = blockIdx.x * 4 + wave;
    if (node >= NN) return;
    int j = lane & 15;
    int slot = lane >> 4;

    // q (pre-scaled by 0.125*log2e): head0 dims j*4..+3, head1 at +64
    uint2 qu0 = *(const uint2*)(qh + (size_t)node * 128 + j * 4);
    uint2 qu1 = *(const uint2*)(qh + (size_t)node * 128 + 64 + j * 4);
    f16x2 q0a = u2h2(qu0.x), q0b = u2h2(qu0.y);
    f16x2 q1a = u2h2(qu1.x), q1b = u2h2(qu1.y);

    float m0 = -1e30f, m1 = -1e30f;
    float l0 = 0.f, l1 = 0.f;
    float acc0[4] = {0.f, 0.f, 0.f, 0.f};
    float acc1[4] = {0.f, 0.f, 0.f, 0.f};

    int st = rowst[node];
    int dg = deg[node];
    int last = dg - 1;
    for (int base = slot * 2; base < dg; base += 8) {
        int s0 = (int)esrc[st + min(base + 0, last)];
        int s1 = (int)esrc[st + min(base + 1, last)];
        const unsigned short* b0 = kvh + (size_t)s0 * 256 + j * 16;
        const unsigned short* b1 = kvh + (size_t)s1 * 256 + j * 16;
        uint4 A0 = *(const uint4*)(b0);       // k0[4],k1[4]
        uint4 B0 = *(const uint4*)(b0 + 8);   // v0[4],v1[4]
        uint4 A1 = *(const uint4*)(b1);
        uint4 B1 = *(const uint4*)(b1 + 8);

        // scores via packed fp16 dot (log2 domain)
        float p00 = dot2acc(q0b, u2h2(A0.y), dot2acc(q0a, u2h2(A0.x), 0.f));
        float p01 = dot2acc(q1b, u2h2(A0.w), dot2acc(q1a, u2h2(A0.z), 0.f));
        float p10 = dot2acc(q0b, u2h2(A1.y), dot2acc(q0a, u2h2(A1.x), 0.f));
        float p11 = dot2acc(q1b, u2h2(A1.w), dot2acc(q1a, u2h2(A1.z), 0.f));
        p00 = wave16_sum(p00);
        p01 = wave16_sum(p01);
        p10 = wave16_sum(p10);
        p11 = wave16_sum(p11);
        if (base + 1 > last) { p10 = -1e30f; p11 = -1e30f; }

        float2 c00 = h2f(B0.x), c01 = h2f(B0.y), c02 = h2f(B0.z), c03 = h2f(B0.w);
        float2 c10 = h2f(B1.x), c11 = h2f(B1.y), c12 = h2f(B1.z), c13 = h2f(B1.w);
        float v00[4] = {c00.x, c00.y, c01.x, c01.y};
        float v01[4] = {c02.x, c02.y, c03.x, c03.y};
        float v10[4] = {c10.x, c10.y, c11.x, c11.y};
        float v11[4] = {c12.x, c12.y, c13.x, c13.y};

        {
            float nm = fmaxf(m0, fmaxf(p00, p10));
            float f = exp2fast(m0 - nm);
            float e0 = exp2fast(p00 - nm);
            float e1 = exp2fast(p10 - nm);
            l0 = l0 * f + e0 + e1;
            #pragma unroll
            for (int r = 0; r < 4; ++r)
                acc0[r] = acc0[r] * f + e0 * v00[r] + e1 * v10[r];
            m0 = nm;
        }
        {
            float nm = fmaxf(m1, fmaxf(p01, p11));
            float f = exp2fast(m1 - nm);
            float e0 = exp2fast(p01 - nm);
            float e1 = exp2fast(p11 - nm);
            l1 = l1 * f + e0 + e1;
            #pragma unroll
            for (int r = 0; r < 4; ++r)
                acc1[r] = acc1[r] * f + e0 * v01[r] + e1 * v11[r];
            m1 = nm;
        }
    }
    // butterfly-merge the 4 slot states (masks 16, 32)
    #pragma unroll
    for (int mask = 16; mask <= 32; mask <<= 1) {
        {
            float mo = __shfl_xor(m0, mask);
            float lo = __shfl_xor(l0, mask);
            float ao[4];
            #pragma unroll
            for (int r = 0; r < 4; ++r) ao[r] = __shfl_xor(acc0[r], mask);
            float nm = fmaxf(m0, mo);
            float fa = exp2fast(m0 - nm);
            float fb = exp2fast(mo - nm);
            l0 = l0 * fa + lo * fb;
            #pragma unroll
            for (int r = 0; r < 4; ++r) acc0[r] = acc0[r] * fa + ao[r] * fb;
            m0 = nm;
        }
        {
            float mo = __shfl_xor(m1, mask);
            float lo = __shfl_xor(l1, mask);
            float ao[4];
            #pragma unroll
            for (int r = 0; r < 4; ++r) ao[r] = __shfl_xor(acc1[r], mask);
            float nm = fmaxf(m1, mo);
            float fa = exp2fast(m1 - nm);
            float fb = exp2fast(mo - nm);
            l1 = l1 * fa + lo * fb;
            #pragma unroll
            for (int r = 0; r < 4; ++r) acc1[r] = acc1[r] * fa + ao[r] * fb;
            m1 = nm;
        }
    }
    float i0 = 1.f / (l0 + 1e-16f);
    float i1 = 1.f / (l1 + 1e-16f);
    uint2 sku = *(const uint2*)(skiph + (size_t)node * 64 + j * 4);
    float2 s0f = h2f(sku.x), s1f = h2f(sku.y);
    float ska[4] = {s0f.x, s0f.y, s1f.x, s1f.y};
    float val[4];
    #pragma unroll
    for (int r = 0; r < 4; ++r) {
        float o = 0.5f * (acc0[r] * i0 + acc1[r] * i1) + ska[r];
        val[r] = fmaxf(o, 0.f);
    }
    if (do_ln) {
        float s = val[0] + val[1] + val[2] + val[3];
        s = wave16_sum(s);
        float mu = s * (1.f / 64.f);
        float ss = 0.f;
        #pragma unroll
        for (int r = 0; r < 4; ++r) { float d = val[r] - mu; ss += d * d; }
        ss = wave16_sum(ss);
        float rstd = rsqrtf(ss * (1.f / 64.f) + 1e-5f);
        float4 g4 = *(const float4*)(gamma + j * 4);
        float4 b4 = *(const float4*)(beta + j * 4);
        float ga[4] = {g4.x, g4.y, g4.z, g4.w};
        float ba[4] = {b4.x, b4.y, b4.z, b4.w};
        #pragma unroll
        for (int r = 0; r < 4; ++r) val[r] = (val[r] - mu) * rstd * ga[r] + ba[r];
    }
    if (slot == 0) {
        ushort4 o = make_ushort4(f2us(val[0]), f2us(val[1]), f2us(val[2]), f2us(val[3]));
        *(ushort4*)(hout + (size_t)node * 64 + j * 4) = o;
    }
}

// ---------------- fused pool + final projection (batch is sorted) ----------------
__device__ __forceinline__ int lbound(const int* __restrict__ a, int n, int key) {
    int lo = 0, hi = n;
    while (lo < hi) {
        int mid = (lo + hi) >> 1;
        if (a[mid] < key) lo = mid + 1; else hi = mid;
    }
    return lo;
}

__global__ __launch_bounds__(256) void pool_final_kernel(
    const unsigned short* __restrict__ h, const int* __restrict__ batch,
    const float* __restrict__ Wout, const float* __restrict__ bout,
    float* __restrict__ out) {
    __shared__ int sh_lo, sh_hi;
    __shared__ float part[4][64];
    int g = blockIdx.x;
    int t = threadIdx.x;
    if (t == 0) {
        sh_lo = lbound(batch, NN, g);
        sh_hi = lbound(batch, NN, g + 1);
    }
    __syncthreads();
    int lo = sh_lo, hi = sh_hi;
    int c = t & 63, w = t >> 6;
    float s = 0.f;
    for (int n = lo + w; n < hi; n += 4) s += us2f(h[(size_t)n * 64 + c]);
    part[w][c] = s;
    __syncthreads();
    if (t < 64) {
        float tot = part[0][t] + part[1][t] + part[2][t] + part[3][t];
        float cnt = (float)(hi - lo);
        float val = tot / fmaxf(cnt, 1.f) * Wout[t];
        #pragma unroll
        for (int mk = 1; mk < 64; mk <<= 1) val += __shfl_xor(val, mk);
        if (t == 0) out[g] = val + bout[0];
    }
}

extern "C" void kernel_launch(void* const* d_in, const int* in_sizes, int n_in,
                              void* d_out, int out_size, void* d_ws, size_t ws_size,
                              hipStream_t stream) {
    const float* x    = (const float*)d_in[0];
    const int*   ei   = (const int*)d_in[1];
    const int*   batch= (const int*)d_in[2];
    const float* Wq   = (const float*)d_in[4];
    const float* bq   = (const float*)d_in[5];
    const float* Wk   = (const float*)d_in[6];
    const float* bk   = (const float*)d_in[7];
    const float* Wv   = (const float*)d_in[8];
    const float* bv   = (const float*)d_in[9];
    const float* Ws   = (const float*)d_in[10];
    const float* bs   = (const float*)d_in[11];
    const float* lng  = (const float*)d_in[12];
    const float* lnb  = (const float*)d_in[13];
    const float* Wout = (const float*)d_in[14];
    const float* bout = (const float*)d_in[15];
    float* out = (float*)d_out;

    unsigned short* qh  = (unsigned short*)d_ws;
    unsigned short* kvh = qh + (size_t)NN * 128;
    unsigned short* skiph = kvh + (size_t)NN * 256;
    unsigned short* xh0 = skiph + (size_t)NN * 64;
    unsigned short* xh1 = xh0 + (size_t)NN * 64;
    unsigned short* wt  = xh1 + (size_t)NN * 64;
    int* deg    = (int*)(wt + 3 * WT_LSTRIDE + 64);  // +64 us: alignment slack
    int* rowst  = deg + NN;
    int* cursor = rowst + NN;
    int* bsum   = cursor + NN;
    unsigned short* esrc = (unsigned short*)(bsum + 256);

    hipMemsetAsync(deg, 0, NN * sizeof(int), stream);

    const int NB = (NN + 255) / 256;  // 196
    // fused: x-cast || W-pack || degree count
    prep_kernel<<<XCAST_BLKS + 21 + DEG_BLKS, 256, 0, stream>>>(
        x, xh0, Wq, Wk, Wv, Ws, wt, ei, deg);
    scan1<<<NB, 256, 0, stream>>>(deg, rowst, bsum);
    scan2<<<1, 256, 0, stream>>>(bsum, NB);
    scan3<<<NB, 256, 0, stream>>>(rowst, deg, bsum, cursor);
    fill_kernel<<<DEG_BLKS, 256, 0, stream>>>(ei, cursor, esrc);

    const int GEMM_GRID = (NN + 31) / 32;  // 1563
    unsigned short* hin = xh0;
    unsigned short* houts[3] = {xh1, xh0, xh1};
    for (int l = 0; l < 3; ++l) {
        gemm_mfma<<<GEMM_GRID, 256, 0, stream>>>(hin, wt + (size_t)l * WT_LSTRIDE,
            bq + (size_t)l * 128, bk + (size_t)l * 128, bv + (size_t)l * 128,
            bs + (size_t)l * 64, qh, kvh, skiph);
        int do_ln = (l < 2) ? 1 : 0;
        agg_kernel<<<(NN + 3) / 4, 256, 0, stream>>>(qh, kvh, skiph, rowst, deg, esrc,
                                                     lng + (size_t)(do_ln ? l : 0) * 64,
                                                     lnb + (size_t)(do_ln ? l : 0) * 64,
                                                     houts[l], do_ln);
        hin = houts[l];
    }
    pool_final_kernel<<<GG, 256, 0, stream>>>(hin, batch, Wout, bout, out);
}

// Round 18
// 386.279 us; speedup vs baseline: 5.8078x; 1.0413x over previous
//
#include <hip/hip_runtime.h>
#include <hip/hip_fp16.h>
#include <math.h>

#define NN 50000
#define EE 800000
#define GG 512

typedef _Float16 f16x8 __attribute__((ext_vector_type(8)));
typedef _Float16 f16x2 __attribute__((ext_vector_type(2)));
typedef float f32x4 __attribute__((ext_vector_type(4)));

#if defined(__has_builtin)
#if __has_builtin(__builtin_amdgcn_fdot2)
#define HAS_FDOT2 1
#endif
#endif

// fold 1/sqrt(64) * log2(e) into q so scores are in log2 domain
#define QSCALE 0.1803368801111244f

__device__ __forceinline__ float wave16_sum(float p) {
    p += __shfl_xor(p, 1);
    p += __shfl_xor(p, 2);
    p += __shfl_xor(p, 4);
    p += __shfl_xor(p, 8);
    return p;
}
__device__ __forceinline__ float2 h2f(unsigned int u) {
    __half2 h = *reinterpret_cast<__half2*>(&u);
    return __half22float2(h);
}
__device__ __forceinline__ unsigned short f2us(float x) {
    return __half_as_ushort(__float2half(x));
}
__device__ __forceinline__ float us2f(unsigned short u) {
    return __half2float(__ushort_as_half(u));
}
__device__ __forceinline__ f16x2 u2h2(unsigned int u) {
    union { unsigned int u; f16x2 h; } x; x.u = u; return x.h;
}
__device__ __forceinline__ float dot2acc(f16x2 a, f16x2 b, float c) {
#ifdef HAS_FDOT2
    return __builtin_amdgcn_fdot2(a, b, c, false);
#else
    return c + (float)a[0] * (float)b[0] + (float)a[1] * (float)b[1];
#endif
}
__device__ __forceinline__ float exp2fast(float x) {
    return __builtin_amdgcn_exp2f(x);
}

// ---------------- degree count ----------------
__global__ void deg_kernel(const int* __restrict__ ei, int* __restrict__ deg) {
    int e = blockIdx.x * 256 + threadIdx.x;
    if (e < EE) atomicAdd(&deg[ei[EE + e]], 1);
}

// ---------------- scans (CSR build) ----------------
__global__ void scan1(const int* __restrict__ deg, int* __restrict__ incl, int* __restrict__ bsum) {
    __shared__ int sh[256];
    int t = threadIdx.x;
    int n = blockIdx.x * 256 + t;
    int vv = (n < NN) ? deg[n] : 0;
    sh[t] = vv; __syncthreads();
    for (int off = 1; off < 256; off <<= 1) {
        int u = (t >= off) ? sh[t - off] : 0;
        __syncthreads();
        sh[t] += u;
        __syncthreads();
    }
    if (n < NN) incl[n] = sh[t];
    if (t == 255) bsum[blockIdx.x] = sh[255];
}

__global__ void scan2(int* __restrict__ bsum, int nblk) {
    __shared__ int sh[256];
    int t = threadIdx.x;
    int vv = (t < nblk) ? bsum[t] : 0;
    sh[t] = vv; __syncthreads();
    for (int off = 1; off < 256; off <<= 1) {
        int u = (t >= off) ? sh[t - off] : 0;
        __syncthreads();
        sh[t] += u;
        __syncthreads();
    }
    bsum[t] = sh[t];
}

__global__ void scan3(int* __restrict__ rowst, const int* __restrict__ deg,
                      const int* __restrict__ bsum, int* __restrict__ cursor) {
    int n = blockIdx.x * 256 + threadIdx.x;
    if (n >= NN) return;
    int off = (blockIdx.x > 0) ? bsum[blockIdx.x - 1] : 0;
    int excl = rowst[n] - deg[n] + off;
    rowst[n] = excl;
    cursor[n] = excl;
}

// ---------------- fused: CSR fill || x-cast || W-pack ----------------
// wt layout per layer: [448][64] fp16, wt[c][k] = W[k][c]; c: 0..127 q, 128..255 k, 256..383 v, 384..447 skip
#define WT_LSTRIDE (448 * 64)
#define FILL_BLKS 3125    // EE/256
#define XCAST_BLKS 3125   // NN*16/256
__global__ void fillprep_kernel(const int* __restrict__ ei, int* __restrict__ cursor,
                                unsigned short* __restrict__ esrc,
                                const float* __restrict__ x, unsigned short* __restrict__ xh,
                                const float* __restrict__ Wq, const float* __restrict__ Wk,
                                const float* __restrict__ Wv, const float* __restrict__ Ws,
                                unsigned short* __restrict__ wt) {
    __shared__ float lds_t[64][65];
    int b = blockIdx.x;
    if (b < FILL_BLKS) {
        int e = b * 256 + threadIdx.x;
        if (e < EE) {
            int s = ei[e], d = ei[EE + e];
            int pos = atomicAdd(&cursor[d], 1);
            esrc[pos] = (unsigned short)s;
        }
        return;
    }
    if (b < FILL_BLKS + XCAST_BLKS) {
        int i = (b - FILL_BLKS) * 256 + threadIdx.x;
        float4 v = *(const float4*)(x + (size_t)i * 4);
        ushort4 o = make_ushort4(f2us(v.x), f2us(v.y), f2us(v.z), f2us(v.w));
        *(ushort4*)(xh + (size_t)i * 4) = o;
        return;
    }
    int tile = b - FILL_BLKS - XCAST_BLKS;  // 0..20
    int l = tile / 7, ct = tile % 7;
    int c0 = ct * 64;
    int t = threadIdx.x;
    #pragma unroll
    for (int r = 0; r < 16; ++r) {
        int idx = r * 256 + t;
        int kk = idx >> 6, cc = idx & 63;
        int c = c0 + cc;
        float val;
        if (c < 384) {
            int m = c >> 7, col = c & 127;
            const float* W = (m == 0) ? Wq : ((m == 1) ? Wk : Wv);
            val = W[(size_t)l * 8192 + kk * 128 + col];
        } else {
            val = Ws[(size_t)l * 4096 + kk * 64 + (c - 384)];
        }
        lds_t[cc][kk] = val;
    }
    __syncthreads();
    #pragma unroll
    for (int r = 0; r < 16; ++r) {
        int idx = r * 256 + t;
        int cc = idx >> 6, kk = idx & 63;
        wt[((size_t)l * 448 + c0 + cc) * 64 + kk] = f2us(lds_t[cc][kk]);
    }
}

// ---------------- MFMA GEMM (LDS-staged coalesced epilogue) ----------------
// kvh row layout (interleaved for agg): group j (0..15) holds halves [j*16, j*16+16):
//   k0[j*4..+3], k1[...], v0[...], v1[...]
__global__ __launch_bounds__(256) void gemm_mfma(
    const unsigned short* __restrict__ xh,
    const unsigned short* __restrict__ wt,
    const float* __restrict__ bq, const float* __restrict__ bk,
    const float* __restrict__ bv, const float* __restrict__ bsk,
    unsigned short* __restrict__ qh, unsigned short* __restrict__ kvh,
    unsigned short* __restrict__ skiph) {
    __shared__ __align__(16) unsigned short lds_q[32 * 128];
    __shared__ __align__(16) unsigned short lds_kv[32 * 256];
    __shared__ __align__(16) unsigned short lds_sk[32 * 64];
    int t = threadIdx.x;
    int wave = t >> 6, lane = t & 63;
    int li = lane & 15, lh = lane >> 4;
    int brow = blockIdx.x * 32;
    int row0 = brow + (wave & 1) * 16;
    int ctbase = (wave >> 1) * 14;

    int arow = min(row0 + li, NN - 1);
    const unsigned short* ap = xh + (size_t)arow * 64 + lh * 8;
    f16x8 a0 = *(const f16x8*)(ap);
    f16x8 a1 = *(const f16x8*)(ap + 32);

    int rl0 = (wave & 1) * 16 + lh * 4;

    #pragma unroll 2
    for (int tt = 0; tt < 14; ++tt) {
        int c = (ctbase + tt) * 16 + li;
        const unsigned short* bp = wt + (size_t)c * 64 + lh * 8;
        f16x8 b0 = *(const f16x8*)(bp);
        f16x8 b1 = *(const f16x8*)(bp + 32);
        f32x4 d = {0.f, 0.f, 0.f, 0.f};
        d = __builtin_amdgcn_mfma_f32_16x16x32_f16(a0, b0, d, 0, 0, 0);
        d = __builtin_amdgcn_mfma_f32_16x16x32_f16(a1, b1, d, 0, 0, 0);
        if (c < 128) {
            float bias = bq[c];
            #pragma unroll
            for (int e = 0; e < 4; ++e)
                lds_q[(rl0 + e) * 128 + c] = f2us((d[e] + bias) * QSCALE);
        } else if (c < 256) {
            int ch = c - 128;
            float bias = bk[ch];
            int off = (ch < 64) ? ((ch >> 2) * 16 + (ch & 3))
                                : (((ch - 64) >> 2) * 16 + 4 + (ch & 3));
            #pragma unroll
            for (int e = 0; e < 4; ++e)
                lds_kv[(rl0 + e) * 256 + off] = f2us(d[e] + bias);
        } else if (c < 384) {
            int ch = c - 256;
            float bias = bv[ch];
            int off = 8 + ((ch < 64) ? ((ch >> 2) * 16 + (ch & 3))
                                     : (((ch - 64) >> 2) * 16 + 4 + (ch & 3)));
            #pragma unroll
            for (int e = 0; e < 4; ++e)
                lds_kv[(rl0 + e) * 256 + off] = f2us(d[e] + bias);
        } else {
            int ch = c - 384;
            float bias = bsk[ch];
            #pragma unroll
            for (int e = 0; e < 4; ++e)
                lds_sk[(rl0 + e) * 64 + ch] = f2us(d[e] + bias);
        }
    }
    __syncthreads();
    // coalesced write-out: rows brow..brow+31 contiguous in each output array
    #pragma unroll
    for (int i = t; i < 512; i += 256) {          // q: 32 rows x 128h = 512 x 16B
        int r = i >> 4, gr = brow + r;
        if (gr < NN)
            *(uint4*)(qh + (size_t)gr * 128 + (i & 15) * 8) = ((const uint4*)lds_q)[i];
    }
    #pragma unroll
    for (int i = t; i < 1024; i += 256) {         // kv: 32 rows x 256h = 1024 x 16B
        int r = i >> 5, gr = brow + r;
        if (gr < NN)
            *(uint4*)(kvh + (size_t)gr * 256 + (i & 31) * 8) = ((const uint4*)lds_kv)[i];
    }
    {
        int i = t;                                 // skip: 32 rows x 64h = 256 x 16B
        int r = i >> 3, gr = brow + r;
        if (i < 256 && gr < NN)
            *(uint4*)(skiph + (size_t)gr * 64 + (i & 7) * 8) = ((const uint4*)lds_sk)[i];
    }
}

// ---------------- per-node attention aggregation (static 4 nodes/block) ----------------
__global__ __launch_bounds__(256) void agg_kernel(
    const unsigned short* __restrict__ qh, const unsigned short* __restrict__ kvh,
    const unsigned short* __restrict__ skiph,
    const int* __restrict__ rowst, const int* __restrict__ deg,
    const unsigned short* __restrict__ esrc, const float* __restrict__ gamma,
    const float* __restrict__ beta, unsigned short* __restrict__ hout, int do_ln) {
    int wave = threadIdx.x >> 6;
    int lane = threadIdx.x & 63;
    int node = blockIdx.x * 4 + wave;
    if (node >= NN) return;
    int j = lane & 15;
    int slot = lane >> 4;

    // q (pre-scaled by 0.125*log2e): head0 dims j*4..+3, head1 at +64
    uint2 qu0 = *(const uint2*)(qh + (size_t)node * 128 + j * 4);
    uint2 qu1 = *(const uint2*)(qh + (size_t)node * 128 + 64 + j * 4);
    f16x2 q0a = u2h2(qu0.x), q0b = u2h2(qu0.y);
    f16x2 q1a = u2h2(qu1.x), q1b = u2h2(qu1.y);

    float m0 = -1e30f, m1 = -1e30f;
    float l0 = 0.f, l1 = 0.f;
    float acc0[4] = {0.f, 0.f, 0.f, 0.f};
    float acc1[4] = {0.f, 0.f, 0.f, 0.f};

    int st = rowst[node];
    int dg = deg[node];
    int last = dg - 1;
    for (int base = slot * 2; base < dg; base += 8) {
        int s0 = (int)esrc[st + min(base + 0, last)];
        int s1 = (int)esrc[st + min(base + 1, last)];
        const unsigned short* b0 = kvh + (size_t)s0 * 256 + j * 16;
        const unsigned short* b1 = kvh + (size_t)s1 * 256 + j * 16;
        uint4 A0 = *(const uint4*)(b0);       // k0[4],k1[4]
        uint4 B0 = *(const uint4*)(b0 + 8);   // v0[4],v1[4]
        uint4 A1 = *(const uint4*)(b1);
        uint4 B1 = *(const uint4*)(b1 + 8);

        // scores via packed fp16 dot (log2 domain)
        float p00 = dot2acc(q0b, u2h2(A0.y), dot2acc(q0a, u2h2(A0.x), 0.f));
        float p01 = dot2acc(q1b, u2h2(A0.w), dot2acc(q1a, u2h2(A0.z), 0.f));
        float p10 = dot2acc(q0b, u2h2(A1.y), dot2acc(q0a, u2h2(A1.x), 0.f));
        float p11 = dot2acc(q1b, u2h2(A1.w), dot2acc(q1a, u2h2(A1.z), 0.f));
        p00 = wave16_sum(p00);
        p01 = wave16_sum(p01);
        p10 = wave16_sum(p10);
        p11 = wave16_sum(p11);
        if (base + 1 > last) { p10 = -1e30f; p11 = -1e30f; }

        float2 c00 = h2f(B0.x), c01 = h2f(B0.y), c02 = h2f(B0.z), c03 = h2f(B0.w);
        float2 c10 = h2f(B1.x), c11 = h2f(B1.y), c12 = h2f(B1.z), c13 = h2f(B1.w);
        float v00[4] = {c00.x, c00.y, c01.x, c01.y};
        float v01[4] = {c02.x, c02.y, c03.x, c03.y};
        float v10[4] = {c10.x, c10.y, c11.x, c11.y};
        float v11[4] = {c12.x, c12.y, c13.x, c13.y};

        {
            float nm = fmaxf(m0, fmaxf(p00, p10));
            float f = exp2fast(m0 - nm);
            float e0 = exp2fast(p00 - nm);
            float e1 = exp2fast(p10 - nm);
            l0 = l0 * f + e0 + e1;
            #pragma unroll
            for (int r = 0; r < 4; ++r)
                acc0[r] = acc0[r] * f + e0 * v00[r] + e1 * v10[r];
            m0 = nm;
        }
        {
            float nm = fmaxf(m1, fmaxf(p01, p11));
            float f = exp2fast(m1 - nm);
            float e0 = exp2fast(p01 - nm);
            float e1 = exp2fast(p11 - nm);
            l1 = l1 * f + e0 + e1;
            #pragma unroll
            for (int r = 0; r < 4; ++r)
                acc1[r] = acc1[r] * f + e0 * v01[r] + e1 * v11[r];
            m1 = nm;
        }
    }
    // butterfly-merge the 4 slot states (masks 16, 32)
    #pragma unroll
    for (int mask = 16; mask <= 32; mask <<= 1) {
        {
            float mo = __shfl_xor(m0, mask);
            float lo = __shfl_xor(l0, mask);
            float ao[4];
            #pragma unroll
            for (int r = 0; r < 4; ++r) ao[r] = __shfl_xor(acc0[r], mask);
            float nm = fmaxf(m0, mo);
            float fa = exp2fast(m0 - nm);
            float fb = exp2fast(mo - nm);
            l0 = l0 * fa + lo * fb;
            #pragma unroll
            for (int r = 0; r < 4; ++r) acc0[r] = acc0[r] * fa + ao[r] * fb;
            m0 = nm;
        }
        {
            float mo = __shfl_xor(m1, mask);
            float lo = __shfl_xor(l1, mask);
            float ao[4];
            #pragma unroll
            for (int r = 0; r < 4; ++r) ao[r] = __shfl_xor(acc1[r], mask);
            float nm = fmaxf(m1, mo);
            float fa = exp2fast(m1 - nm);
            float fb = exp2fast(mo - nm);
            l1 = l1 * fa + lo * fb;
            #pragma unroll
            for (int r = 0; r < 4; ++r) acc1[r] = acc1[r] * fa + ao[r] * fb;
            m1 = nm;
        }
    }
    float i0 = 1.f / (l0 + 1e-16f);
    float i1 = 1.f / (l1 + 1e-16f);
    uint2 sku = *(const uint2*)(skiph + (size_t)node * 64 + j * 4);
    float2 s0f = h2f(sku.x), s1f = h2f(sku.y);
    float ska[4] = {s0f.x, s0f.y, s1f.x, s1f.y};
    float val[4];
    #pragma unroll
    for (int r = 0; r < 4; ++r) {
        float o = 0.5f * (acc0[r] * i0 + acc1[r] * i1) + ska[r];
        val[r] = fmaxf(o, 0.f);
    }
    if (do_ln) {
        float s = val[0] + val[1] + val[2] + val[3];
        s = wave16_sum(s);
        float mu = s * (1.f / 64.f);
        float ss = 0.f;
        #pragma unroll
        for (int r = 0; r < 4; ++r) { float d = val[r] - mu; ss += d * d; }
        ss = wave16_sum(ss);
        float rstd = rsqrtf(ss * (1.f / 64.f) + 1e-5f);
        float4 g4 = *(const float4*)(gamma + j * 4);
        float4 b4 = *(const float4*)(beta + j * 4);
        float ga[4] = {g4.x, g4.y, g4.z, g4.w};
        float ba[4] = {b4.x, b4.y, b4.z, b4.w};
        #pragma unroll
        for (int r = 0; r < 4; ++r) val[r] = (val[r] - mu) * rstd * ga[r] + ba[r];
    }
    if (slot == 0) {
        ushort4 o = make_ushort4(f2us(val[0]), f2us(val[1]), f2us(val[2]), f2us(val[3]));
        *(ushort4*)(hout + (size_t)node * 64 + j * 4) = o;
    }
}

// ---------------- fused pool + final projection (batch is sorted) ----------------
__device__ __forceinline__ int lbound(const int* __restrict__ a, int n, int key) {
    int lo = 0, hi = n;
    while (lo < hi) {
        int mid = (lo + hi) >> 1;
        if (a[mid] < key) lo = mid + 1; else hi = mid;
    }
    return lo;
}

__global__ __launch_bounds__(256) void pool_final_kernel(
    const unsigned short* __restrict__ h, const int* __restrict__ batch,
    const float* __restrict__ Wout, const float* __restrict__ bout,
    float* __restrict__ out) {
    __shared__ int sh_lo, sh_hi;
    __shared__ float part[4][64];
    int g = blockIdx.x;
    int t = threadIdx.x;
    if (t == 0) {
        sh_lo = lbound(batch, NN, g);
        sh_hi = lbound(batch, NN, g + 1);
    }
    __syncthreads();
    int lo = sh_lo, hi = sh_hi;
    int c = t & 63, w = t >> 6;
    float s = 0.f;
    for (int n = lo + w; n < hi; n += 4) s += us2f(h[(size_t)n * 64 + c]);
    part[w][c] = s;
    __syncthreads();
    if (t < 64) {
        float tot = part[0][t] + part[1][t] + part[2][t] + part[3][t];
        float cnt = (float)(hi - lo);
        float val = tot / fmaxf(cnt, 1.f) * Wout[t];
        #pragma unroll
        for (int mk = 1; mk < 64; mk <<= 1) val += __shfl_xor(val, mk);
        if (t == 0) out[g] = val + bout[0];
    }
}

extern "C" void kernel_launch(void* const* d_in, const int* in_sizes, int n_in,
                              void* d_out, int out_size, void* d_ws, size_t ws_size,
                              hipStream_t stream) {
    const float* x    = (const float*)d_in[0];
    const int*   ei   = (const int*)d_in[1];
    const int*   batch= (const int*)d_in[2];
    const float* Wq   = (const float*)d_in[4];
    const float* bq   = (const float*)d_in[5];
    const float* Wk   = (const float*)d_in[6];
    const float* bk   = (const float*)d_in[7];
    const float* Wv   = (const float*)d_in[8];
    const float* bv   = (const float*)d_in[9];
    const float* Ws   = (const float*)d_in[10];
    const float* bs   = (const float*)d_in[11];
    const float* lng  = (const float*)d_in[12];
    const float* lnb  = (const float*)d_in[13];
    const float* Wout = (const float*)d_in[14];
    const float* bout = (const float*)d_in[15];
    float* out = (float*)d_out;

    unsigned short* qh  = (unsigned short*)d_ws;
    unsigned short* kvh = qh + (size_t)NN * 128;
    unsigned short* skiph = kvh + (size_t)NN * 256;
    unsigned short* xh0 = skiph + (size_t)NN * 64;
    unsigned short* xh1 = xh0 + (size_t)NN * 64;
    unsigned short* wt  = xh1 + (size_t)NN * 64;
    int* deg    = (int*)(wt + 3 * WT_LSTRIDE + 64);  // +64 us: alignment slack
    int* rowst  = deg + NN;
    int* cursor = rowst + NN;
    int* bsum   = cursor + NN;
    unsigned short* esrc = (unsigned short*)(bsum + 256);

    hipMemsetAsync(deg, 0, NN * sizeof(int), stream);

    const int NB = (NN + 255) / 256;  // 196
    deg_kernel<<<FILL_BLKS, 256, 0, stream>>>(ei, deg);
    scan1<<<NB, 256, 0, stream>>>(deg, rowst, bsum);
    scan2<<<1, 256, 0, stream>>>(bsum, NB);
    scan3<<<NB, 256, 0, stream>>>(rowst, deg, bsum, cursor);
    // fused: CSR fill || x-cast || W-pack (fill blocks dispatched first)
    fillprep_kernel<<<FILL_BLKS + XCAST_BLKS + 21, 256, 0, stream>>>(
        ei, cursor, esrc, x, xh0, Wq, Wk, Wv, Ws, wt);

    const int GEMM_GRID = (NN + 31) / 32;  // 1563
    unsigned short* hin = xh0;
    unsigned short* houts[3] = {xh1, xh0, xh1};
    for (int l = 0; l < 3; ++l) {
        gemm_mfma<<<GEMM_GRID, 256, 0, stream>>>(hin, wt + (size_t)l * WT_LSTRIDE,
            bq + (size_t)l * 128, bk + (size_t)l * 128, bv + (size_t)l * 128,
            bs + (size_t)l * 64, qh, kvh, skiph);
        int do_ln = (l < 2) ? 1 : 0;
        agg_kernel<<<(NN + 3) / 4, 256, 0, stream>>>(qh, kvh, skiph, rowst, deg, esrc,
                                                     lng + (size_t)(do_ln ? l : 0) * 64,
                                                     lnb + (size_t)(do_ln ? l : 0) * 64,
                                                     houts[l], do_ln);
        hin = houts[l];
    }
    pool_final_kernel<<<GG, 256, 0, stream>>>(hin, batch, Wout, bout, out);
}

// Round 19
// 381.440 us; speedup vs baseline: 5.8815x; 1.0127x over previous
//
#include <hip/hip_runtime.h>
#include <hip/hip_fp16.h>
#include <math.h>

#define NN 50000
#define EE 800000
#define GG 512

typedef _Float16 f16x8 __attribute__((ext_vector_type(8)));
typedef _Float16 f16x2 __attribute__((ext_vector_type(2)));
typedef float f32x4 __attribute__((ext_vector_type(4)));

#if defined(__has_builtin)
#if __has_builtin(__builtin_amdgcn_fdot2)
#define HAS_FDOT2 1
#endif
#endif

// fold 1/sqrt(64) * log2(e) into q so scores are in log2 domain
#define QSCALE 0.1803368801111244f

__device__ __forceinline__ float wave16_sum(float p) {
    p += __shfl_xor(p, 1);
    p += __shfl_xor(p, 2);
    p += __shfl_xor(p, 4);
    p += __shfl_xor(p, 8);
    return p;
}
__device__ __forceinline__ float2 h2f(unsigned int u) {
    __half2 h = *reinterpret_cast<__half2*>(&u);
    return __half22float2(h);
}
__device__ __forceinline__ unsigned short f2us(float x) {
    return __half_as_ushort(__float2half(x));
}
__device__ __forceinline__ float us2f(unsigned short u) {
    return __half2float(__ushort_as_half(u));
}
__device__ __forceinline__ f16x2 u2h2(unsigned int u) {
    union { unsigned int u; f16x2 h; } x; x.u = u; return x.h;
}
__device__ __forceinline__ float dot2acc(f16x2 a, f16x2 b, float c) {
#ifdef HAS_FDOT2
    return __builtin_amdgcn_fdot2(a, b, c, false);
#else
    return c + (float)a[0] * (float)b[0] + (float)a[1] * (float)b[1];
#endif
}
__device__ __forceinline__ float exp2fast(float x) {
    return __builtin_amdgcn_exp2f(x);
}

// ---------------- degree count ----------------
__global__ void deg_kernel(const int* __restrict__ ei, int* __restrict__ deg) {
    int e = blockIdx.x * 256 + threadIdx.x;
    if (e < EE) atomicAdd(&deg[ei[EE + e]], 1);
}

// ---------------- scans (CSR build) ----------------
__global__ void scan1(const int* __restrict__ deg, int* __restrict__ incl, int* __restrict__ bsum) {
    __shared__ int sh[256];
    int t = threadIdx.x;
    int n = blockIdx.x * 256 + t;
    int vv = (n < NN) ? deg[n] : 0;
    sh[t] = vv; __syncthreads();
    for (int off = 1; off < 256; off <<= 1) {
        int u = (t >= off) ? sh[t - off] : 0;
        __syncthreads();
        sh[t] += u;
        __syncthreads();
    }
    if (n < NN) incl[n] = sh[t];
    if (t == 255) bsum[blockIdx.x] = sh[255];
}

__global__ void scan2(int* __restrict__ bsum, int nblk) {
    __shared__ int sh[256];
    int t = threadIdx.x;
    int vv = (t < nblk) ? bsum[t] : 0;
    sh[t] = vv; __syncthreads();
    for (int off = 1; off < 256; off <<= 1) {
        int u = (t >= off) ? sh[t - off] : 0;
        __syncthreads();
        sh[t] += u;
        __syncthreads();
    }
    bsum[t] = sh[t];
}

__global__ void scan3(int* __restrict__ rowst, const int* __restrict__ deg,
                      const int* __restrict__ bsum, int* __restrict__ cursor) {
    int n = blockIdx.x * 256 + threadIdx.x;
    if (n >= NN) return;
    int off = (blockIdx.x > 0) ? bsum[blockIdx.x - 1] : 0;
    int excl = rowst[n] - deg[n] + off;
    rowst[n] = excl;
    cursor[n] = excl;
}

// ---------------- fused: CSR fill || x-cast || W-pack ----------------
// wt layout per layer: [448][64] fp16, wt[c][k] = W[k][c]; c: 0..127 q, 128..255 k, 256..383 v, 384..447 skip
#define WT_LSTRIDE (448 * 64)
#define FILL_BLKS 3125    // EE/256
#define XCAST_BLKS 3125   // NN*16/256
__global__ void fillprep_kernel(const int* __restrict__ ei, int* __restrict__ cursor,
                                unsigned short* __restrict__ esrc,
                                const float* __restrict__ x, unsigned short* __restrict__ xh,
                                const float* __restrict__ Wq, const float* __restrict__ Wk,
                                const float* __restrict__ Wv, const float* __restrict__ Ws,
                                unsigned short* __restrict__ wt) {
    __shared__ float lds_t[64][65];
    int b = blockIdx.x;
    if (b < FILL_BLKS) {
        int e = b * 256 + threadIdx.x;
        if (e < EE) {
            int s = ei[e], d = ei[EE + e];
            int pos = atomicAdd(&cursor[d], 1);
            esrc[pos] = (unsigned short)s;
        }
        return;
    }
    if (b < FILL_BLKS + XCAST_BLKS) {
        int i = (b - FILL_BLKS) * 256 + threadIdx.x;
        float4 v = *(const float4*)(x + (size_t)i * 4);
        ushort4 o = make_ushort4(f2us(v.x), f2us(v.y), f2us(v.z), f2us(v.w));
        *(ushort4*)(xh + (size_t)i * 4) = o;
        return;
    }
    int tile = b - FILL_BLKS - XCAST_BLKS;  // 0..20
    int l = tile / 7, ct = tile % 7;
    int c0 = ct * 64;
    int t = threadIdx.x;
    #pragma unroll
    for (int r = 0; r < 16; ++r) {
        int idx = r * 256 + t;
        int kk = idx >> 6, cc = idx & 63;
        int c = c0 + cc;
        float val;
        if (c < 384) {
            int m = c >> 7, col = c & 127;
            const float* W = (m == 0) ? Wq : ((m == 1) ? Wk : Wv);
            val = W[(size_t)l * 8192 + kk * 128 + col];
        } else {
            val = Ws[(size_t)l * 4096 + kk * 64 + (c - 384)];
        }
        lds_t[cc][kk] = val;
    }
    __syncthreads();
    #pragma unroll
    for (int r = 0; r < 16; ++r) {
        int idx = r * 256 + t;
        int cc = idx >> 6, kk = idx & 63;
        wt[((size_t)l * 448 + c0 + cc) * 64 + kk] = f2us(lds_t[cc][kk]);
    }
}

// ---------------- MFMA GEMM (LDS-staged coalesced epilogue) ----------------
// kvh row layout (interleaved for agg): group j (0..15) holds halves [j*16, j*16+16):
//   k0[j*4..+3] (4), k1[j*4..+3] (4), then v pairs: (v0[j*4+r], v1[j*4+r]) for r=0..3 (8)
__global__ __launch_bounds__(256) void gemm_mfma(
    const unsigned short* __restrict__ xh,
    const unsigned short* __restrict__ wt,
    const float* __restrict__ bq, const float* __restrict__ bk,
    const float* __restrict__ bv, const float* __restrict__ bsk,
    unsigned short* __restrict__ qh, unsigned short* __restrict__ kvh,
    unsigned short* __restrict__ skiph) {
    __shared__ __align__(16) unsigned short lds_q[32 * 128];
    __shared__ __align__(16) unsigned short lds_kv[32 * 256];
    __shared__ __align__(16) unsigned short lds_sk[32 * 64];
    int t = threadIdx.x;
    int wave = t >> 6, lane = t & 63;
    int li = lane & 15, lh = lane >> 4;
    int brow = blockIdx.x * 32;
    int row0 = brow + (wave & 1) * 16;
    int ctbase = (wave >> 1) * 14;

    int arow = min(row0 + li, NN - 1);
    const unsigned short* ap = xh + (size_t)arow * 64 + lh * 8;
    f16x8 a0 = *(const f16x8*)(ap);
    f16x8 a1 = *(const f16x8*)(ap + 32);

    int rl0 = (wave & 1) * 16 + lh * 4;

    #pragma unroll 2
    for (int tt = 0; tt < 14; ++tt) {
        int c = (ctbase + tt) * 16 + li;
        const unsigned short* bp = wt + (size_t)c * 64 + lh * 8;
        f16x8 b0 = *(const f16x8*)(bp);
        f16x8 b1 = *(const f16x8*)(bp + 32);
        f32x4 d = {0.f, 0.f, 0.f, 0.f};
        d = __builtin_amdgcn_mfma_f32_16x16x32_f16(a0, b0, d, 0, 0, 0);
        d = __builtin_amdgcn_mfma_f32_16x16x32_f16(a1, b1, d, 0, 0, 0);
        if (c < 128) {
            float bias = bq[c];
            #pragma unroll
            for (int e = 0; e < 4; ++e)
                lds_q[(rl0 + e) * 128 + c] = f2us((d[e] + bias) * QSCALE);
        } else if (c < 256) {
            int ch = c - 128;
            float bias = bk[ch];
            int off = (ch < 64) ? ((ch >> 2) * 16 + (ch & 3))
                                : (((ch - 64) >> 2) * 16 + 4 + (ch & 3));
            #pragma unroll
            for (int e = 0; e < 4; ++e)
                lds_kv[(rl0 + e) * 256 + off] = f2us(d[e] + bias);
        } else if (c < 384) {
            int ch = c - 256;
            float bias = bv[ch];
            int head = ch >> 6, col = ch & 63;
            int off = (col >> 2) * 16 + 8 + (col & 3) * 2 + head;
            #pragma unroll
            for (int e = 0; e < 4; ++e)
                lds_kv[(rl0 + e) * 256 + off] = f2us(d[e] + bias);
        } else {
            int ch = c - 384;
            float bias = bsk[ch];
            #pragma unroll
            for (int e = 0; e < 4; ++e)
                lds_sk[(rl0 + e) * 64 + ch] = f2us(d[e] + bias);
        }
    }
    __syncthreads();
    // coalesced write-out: rows brow..brow+31 contiguous in each output array
    #pragma unroll
    for (int i = t; i < 512; i += 256) {          // q: 32 rows x 128h = 512 x 16B
        int r = i >> 4, gr = brow + r;
        if (gr < NN)
            *(uint4*)(qh + (size_t)gr * 128 + (i & 15) * 8) = ((const uint4*)lds_q)[i];
    }
    #pragma unroll
    for (int i = t; i < 1024; i += 256) {         // kv: 32 rows x 256h = 1024 x 16B
        int r = i >> 5, gr = brow + r;
        if (gr < NN)
            *(uint4*)(kvh + (size_t)gr * 256 + (i & 31) * 8) = ((const uint4*)lds_kv)[i];
    }
    {
        int i = t;                                 // skip: 32 rows x 64h = 256 x 16B
        int r = i >> 3, gr = brow + r;
        if (i < 256 && gr < NN)
            *(uint4*)(skiph + (size_t)gr * 64 + (i & 7) * 8) = ((const uint4*)lds_sk)[i];
    }
}

// ---------------- per-node attention aggregation (pk-fp16 accumulator) ----------------
__global__ __launch_bounds__(256) void agg_kernel(
    const unsigned short* __restrict__ qh, const unsigned short* __restrict__ kvh,
    const unsigned short* __restrict__ skiph,
    const int* __restrict__ rowst, const int* __restrict__ deg,
    const unsigned short* __restrict__ esrc, const float* __restrict__ gamma,
    const float* __restrict__ beta, unsigned short* __restrict__ hout, int do_ln) {
    int wave = threadIdx.x >> 6;
    int lane = threadIdx.x & 63;
    int node = blockIdx.x * 4 + wave;
    if (node >= NN) return;
    int j = lane & 15;
    int slot = lane >> 4;

    // q (pre-scaled by 0.125*log2e): head0 dims j*4..+3, head1 at +64
    uint2 qu0 = *(const uint2*)(qh + (size_t)node * 128 + j * 4);
    uint2 qu1 = *(const uint2*)(qh + (size_t)node * 128 + 64 + j * 4);
    f16x2 q0a = u2h2(qu0.x), q0b = u2h2(qu0.y);
    f16x2 q1a = u2h2(qu1.x), q1b = u2h2(qu1.y);

    float m0 = -1e30f, m1 = -1e30f;
    float l0 = 0.f, l1 = 0.f;
    f16x2 accp[4];
    #pragma unroll
    for (int r = 0; r < 4; ++r) accp[r] = f16x2{(_Float16)0.f, (_Float16)0.f};

    int st = rowst[node];
    int dg = deg[node];
    int last = dg - 1;
    for (int base = slot * 2; base < dg; base += 8) {
        int s0 = (int)esrc[st + min(base + 0, last)];
        int s1 = (int)esrc[st + min(base + 1, last)];
        const unsigned short* b0 = kvh + (size_t)s0 * 256 + j * 16;
        const unsigned short* b1 = kvh + (size_t)s1 * 256 + j * 16;
        uint4 A0 = *(const uint4*)(b0);       // k0[4],k1[4]
        uint4 B0 = *(const uint4*)(b0 + 8);   // (v0,v1) pairs r=0..3
        uint4 A1 = *(const uint4*)(b1);
        uint4 B1 = *(const uint4*)(b1 + 8);

        // scores via packed fp16 dot (log2 domain)
        float p00 = dot2acc(q0b, u2h2(A0.y), dot2acc(q0a, u2h2(A0.x), 0.f));
        float p01 = dot2acc(q1b, u2h2(A0.w), dot2acc(q1a, u2h2(A0.z), 0.f));
        float p10 = dot2acc(q0b, u2h2(A1.y), dot2acc(q0a, u2h2(A1.x), 0.f));
        float p11 = dot2acc(q1b, u2h2(A1.w), dot2acc(q1a, u2h2(A1.z), 0.f));
        p00 = wave16_sum(p00);
        p01 = wave16_sum(p01);
        p10 = wave16_sum(p10);
        p11 = wave16_sum(p11);
        if (base + 1 > last) { p10 = -1e30f; p11 = -1e30f; }

        float nm0 = fmaxf(m0, fmaxf(p00, p10));
        float nm1 = fmaxf(m1, fmaxf(p01, p11));
        float f0 = exp2fast(m0 - nm0);
        float f1 = exp2fast(m1 - nm1);
        float e00 = exp2fast(p00 - nm0);
        float e01 = exp2fast(p01 - nm1);
        float e10 = exp2fast(p10 - nm0);
        float e11 = exp2fast(p11 - nm1);
        l0 = l0 * f0 + e00 + e10;
        l1 = l1 * f1 + e01 + e11;
        m0 = nm0; m1 = nm1;
        f16x2 fpk  = {(_Float16)f0,  (_Float16)f1};
        f16x2 e0pk = {(_Float16)e00, (_Float16)e01};
        f16x2 e1pk = {(_Float16)e10, (_Float16)e11};
        unsigned int vb0[4] = {B0.x, B0.y, B0.z, B0.w};
        unsigned int vb1[4] = {B1.x, B1.y, B1.z, B1.w};
        #pragma unroll
        for (int r = 0; r < 4; ++r)
            accp[r] = accp[r] * fpk + e0pk * u2h2(vb0[r]) + e1pk * u2h2(vb1[r]);
    }
    // butterfly-merge the 4 slot states (masks 16, 32)
    #pragma unroll
    for (int mask = 16; mask <= 32; mask <<= 1) {
        float mo0 = __shfl_xor(m0, mask);
        float lo0 = __shfl_xor(l0, mask);
        float mo1 = __shfl_xor(m1, mask);
        float lo1 = __shfl_xor(l1, mask);
        int ai[4];
        #pragma unroll
        for (int r = 0; r < 4; ++r) {
            union { f16x2 h; int i; } u; u.h = accp[r];
            ai[r] = __shfl_xor(u.i, mask);
        }
        float nm0 = fmaxf(m0, mo0);
        float nm1 = fmaxf(m1, mo1);
        float fa0 = exp2fast(m0 - nm0), fb0 = exp2fast(mo0 - nm0);
        float fa1 = exp2fast(m1 - nm1), fb1 = exp2fast(mo1 - nm1);
        l0 = l0 * fa0 + lo0 * fb0;
        l1 = l1 * fa1 + lo1 * fb1;
        m0 = nm0; m1 = nm1;
        f16x2 fapk = {(_Float16)fa0, (_Float16)fa1};
        f16x2 fbpk = {(_Float16)fb0, (_Float16)fb1};
        #pragma unroll
        for (int r = 0; r < 4; ++r) {
            union { int i; f16x2 h; } u; u.i = ai[r];
            accp[r] = accp[r] * fapk + u.h * fbpk;
        }
    }
    float i0 = 1.f / (l0 + 1e-16f);
    float i1 = 1.f / (l1 + 1e-16f);
    uint2 sku = *(const uint2*)(skiph + (size_t)node * 64 + j * 4);
    float2 s0f = h2f(sku.x), s1f = h2f(sku.y);
    float ska[4] = {s0f.x, s0f.y, s1f.x, s1f.y};
    float val[4];
    #pragma unroll
    for (int r = 0; r < 4; ++r) {
        float a0 = (float)accp[r][0];
        float a1 = (float)accp[r][1];
        float o = 0.5f * (a0 * i0 + a1 * i1) + ska[r];
        val[r] = fmaxf(o, 0.f);
    }
    if (do_ln) {
        float s = val[0] + val[1] + val[2] + val[3];
        s = wave16_sum(s);
        float mu = s * (1.f / 64.f);
        float ss = 0.f;
        #pragma unroll
        for (int r = 0; r < 4; ++r) { float d = val[r] - mu; ss += d * d; }
        ss = wave16_sum(ss);
        float rstd = rsqrtf(ss * (1.f / 64.f) + 1e-5f);
        float4 g4 = *(const float4*)(gamma + j * 4);
        float4 b4 = *(const float4*)(beta + j * 4);
        float ga[4] = {g4.x, g4.y, g4.z, g4.w};
        float ba[4] = {b4.x, b4.y, b4.z, b4.w};
        #pragma unroll
        for (int r = 0; r < 4; ++r) val[r] = (val[r] - mu) * rstd * ga[r] + ba[r];
    }
    if (slot == 0) {
        ushort4 o = make_ushort4(f2us(val[0]), f2us(val[1]), f2us(val[2]), f2us(val[3]));
        *(ushort4*)(hout + (size_t)node * 64 + j * 4) = o;
    }
}

// ---------------- fused pool + final projection (batch is sorted) ----------------
__device__ __forceinline__ int lbound(const int* __restrict__ a, int n, int key) {
    int lo = 0, hi = n;
    while (lo < hi) {
        int mid = (lo + hi) >> 1;
        if (a[mid] < key) lo = mid + 1; else hi = mid;
    }
    return lo;
}

__global__ __launch_bounds__(256) void pool_final_kernel(
    const unsigned short* __restrict__ h, const int* __restrict__ batch,
    const float* __restrict__ Wout, const float* __restrict__ bout,
    float* __restrict__ out) {
    __shared__ int sh_lo, sh_hi;
    __shared__ float part[4][64];
    int g = blockIdx.x;
    int t = threadIdx.x;
    if (t == 0) {
        sh_lo = lbound(batch, NN, g);
        sh_hi = lbound(batch, NN, g + 1);
    }
    __syncthreads();
    int lo = sh_lo, hi = sh_hi;
    int c = t & 63, w = t >> 6;
    float s = 0.f;
    for (int n = lo + w; n < hi; n += 4) s += us2f(h[(size_t)n * 64 + c]);
    part[w][c] = s;
    __syncthreads();
    if (t < 64) {
        float tot = part[0][t] + part[1][t] + part[2][t] + part[3][t];
        float cnt = (float)(hi - lo);
        float val = tot / fmaxf(cnt, 1.f) * Wout[t];
        #pragma unroll
        for (int mk = 1; mk < 64; mk <<= 1) val += __shfl_xor(val, mk);
        if (t == 0) out[g] = val + bout[0];
    }
}

extern "C" void kernel_launch(void* const* d_in, const int* in_sizes, int n_in,
                              void* d_out, int out_size, void* d_ws, size_t ws_size,
                              hipStream_t stream) {
    const float* x    = (const float*)d_in[0];
    const int*   ei   = (const int*)d_in[1];
    const int*   batch= (const int*)d_in[2];
    const float* Wq   = (const float*)d_in[4];
    const float* bq   = (const float*)d_in[5];
    const float* Wk   = (const float*)d_in[6];
    const float* bk   = (const float*)d_in[7];
    const float* Wv   = (const float*)d_in[8];
    const float* bv   = (const float*)d_in[9];
    const float* Ws   = (const float*)d_in[10];
    const float* bs   = (const float*)d_in[11];
    const float* lng  = (const float*)d_in[12];
    const float* lnb  = (const float*)d_in[13];
    const float* Wout = (const float*)d_in[14];
    const float* bout = (const float*)d_in[15];
    float* out = (float*)d_out;

    unsigned short* qh  = (unsigned short*)d_ws;
    unsigned short* kvh = qh + (size_t)NN * 128;
    unsigned short* skiph = kvh + (size_t)NN * 256;
    unsigned short* xh0 = skiph + (size_t)NN * 64;
    unsigned short* xh1 = xh0 + (size_t)NN * 64;
    unsigned short* wt  = xh1 + (size_t)NN * 64;
    int* deg    = (int*)(wt + 3 * WT_LSTRIDE + 64);  // +64 us: alignment slack
    int* rowst  = deg + NN;
    int* cursor = rowst + NN;
    int* bsum   = cursor + NN;
    unsigned short* esrc = (unsigned short*)(bsum + 256);

    hipMemsetAsync(deg, 0, NN * sizeof(int), stream);

    const int NB = (NN + 255) / 256;  // 196
    deg_kernel<<<FILL_BLKS, 256, 0, stream>>>(ei, deg);
    scan1<<<NB, 256, 0, stream>>>(deg, rowst, bsum);
    scan2<<<1, 256, 0, stream>>>(bsum, NB);
    scan3<<<NB, 256, 0, stream>>>(rowst, deg, bsum, cursor);
    // fused: CSR fill || x-cast || W-pack (fill blocks dispatched first)
    fillprep_kernel<<<FILL_BLKS + XCAST_BLKS + 21, 256, 0, stream>>>(
        ei, cursor, esrc, x, xh0, Wq, Wk, Wv, Ws, wt);

    const int GEMM_GRID = (NN + 31) / 32;  // 1563
    unsigned short* hin = xh0;
    unsigned short* houts[3] = {xh1, xh0, xh1};
    for (int l = 0; l < 3; ++l) {
        gemm_mfma<<<GEMM_GRID, 256, 0, stream>>>(hin, wt + (size_t)l * WT_LSTRIDE,
            bq + (size_t)l * 128, bk + (size_t)l * 128, bv + (size_t)l * 128,
            bs + (size_t)l * 64, qh, kvh, skiph);
        int do_ln = (l < 2) ? 1 : 0;
        agg_kernel<<<(NN + 3) / 4, 256, 0, stream>>>(qh, kvh, skiph, rowst, deg, esrc,
                                                     lng + (size_t)(do_ln ? l : 0) * 64,
                                                     lnb + (size_t)(do_ln ? l : 0) * 64,
                                                     houts[l], do_ln);
        hin = houts[l];
    }
    pool_final_kernel<<<GG, 256, 0, stream>>>(hin, batch, Wout, bout, out);
}